// Round 12
// baseline (205.061 us; speedup 1.0000x reference)
//
#include <hip/hip_runtime.h>
#include <hip/hip_fp16.h>
#include <cstdint>

#define N_NODES 4096
#define IN_FEAT 256
#define OUT_FEAT 64
#define NHEAD 8
#define LOG2E 1.4426950408889634f

typedef _Float16 f16;
typedef f16   f16x2 __attribute__((ext_vector_type(2)));
typedef f16   f16x8 __attribute__((ext_vector_type(8)));
typedef float f32x4 __attribute__((ext_vector_type(4)));

// ws layout (bytes) — total 30,015,488 (< 38.8 MB proven in r3):
//   h_t   @ 0        : 8*64*4096*2 = 4194304   f16 [h][feat][node]
//   srcPK @ 4194304  : 8*4096*4    = 131072    dword {E1s,E5s} f16 pair per (h,n)
//   dstE1 @ 4325376  : 8*4096*2    = 65536     f16 exp2(t_d) per (h,m)
//   dstE5 @ 4390912  : 8*4096*2    = 65536     f16 exp2(0.2 t_d)
//   Wt    @ 4456448  : 8*64*256*2  = 262144    f16 [h][col][k]
//   emask @ 4718592  : 4096*4096   = 16777216  byte 0xFF/0x00 = adj!=0
//   numA  @ 21495808 : 4096*8*64*4 = 8388608   f32 atomic accumulators
//   denA  @ 29884416 : 4096*8*4    = 131072
#define OFF_SRCPK 4194304
#define OFF_DSTE1 4325376
#define OFF_DSTE5 4390912
#define OFF_WT    4456448
#define OFF_EM    4718592
#define OFF_NUMA  21495808ULL
#define OFF_DENA  29884416ULL

union HU { unsigned u; f16x2 h; };
union A8 { f16x8 v; unsigned u[4]; };

__device__ __forceinline__ void async_copy16(const void* g, void* l) {
    __builtin_amdgcn_global_load_lds(
        (const __attribute__((address_space(1))) void*)g,
        (__attribute__((address_space(3))) void*)l, 16, 0, 0);
}

static __device__ inline unsigned pkh2(float a, float b) {
    union { f16 h[2]; unsigned u; } t;
    t.h[0] = (f16)a; t.h[1] = (f16)b; return t.u;
}

// ---------------------------------------------------------------------------
// Pack kernel, 3 branches by blockIdx:
//   [0,1024)      adj -> emask bytes (elementwise, fully coalesced, no atomics)
//   [1024,1088)   prepack Wt[hd][col][k] = f16 W[hd][k][col]
//   [1088,2128)   zero numA/denA
// ---------------------------------------------------------------------------
__global__ __launch_bounds__(256) void gat_pack(
    const int* __restrict__ adj, unsigned* __restrict__ em32,
    const float* __restrict__ W, f16* __restrict__ Wt,
    float* __restrict__ zeroBase)
{
    if (blockIdx.x >= 1088) {   // zero branch: 1040 blocks x 2048 floats
        size_t off = ((size_t)(blockIdx.x - 1088) * 256 + threadIdx.x) * 8;
        float4 z = {0.f, 0.f, 0.f, 0.f};
        *(float4*)(zeroBase + off)     = z;
        *(float4*)(zeroBase + off + 4) = z;
        return;
    }
    if (blockIdx.x >= 1024) {   // prepack branch
        int gid = (blockIdx.x - 1024) * 256 + threadIdx.x;   // 0..16383
        int hd  = gid >> 11;
        int rem = gid & 2047;
        int c   = rem >> 5;
        int kg  = rem & 31;
        const float* src = W + ((size_t)hd * IN_FEAT + kg * 8) * OUT_FEAT + c;
        f16x8 v;
        #pragma unroll
        for (int t = 0; t < 8; ++t) v[t] = (f16)src[(size_t)t * OUT_FEAT];
        *(f16x8*)(Wt + ((size_t)hd * OUT_FEAT + c) * IN_FEAT + kg * 8) = v;
        return;
    }

    // emask branch: wave per row, 16 steps of int4->4 mask bytes (1 dword)
    const int wv   = threadIdx.x >> 6;
    const int lane = threadIdx.x & 63;
    const int row  = blockIdx.x * 4 + wv;
    const int* p   = adj + (size_t)row * N_NODES;
    unsigned* dst  = em32 + (size_t)row * (N_NODES / 4);
    #pragma unroll 4
    for (int s = 0; s < 16; ++s) {
        int4 v = *(const int4*)(p + s * 256 + lane * 4);
        unsigned d = (v.x ? 0x000000FFu : 0u) | (v.y ? 0x0000FF00u : 0u)
                   | (v.z ? 0x00FF0000u : 0u) | (v.w ? 0xFF000000u : 0u);
        dst[s * 64 + lane] = d;
    }
}

// ---------------------------------------------------------------------------
// Phase 1: h = x @ W[h] (f16 MFMA). Epilogue stores factored exponentials.
// 512 blocks x 256 thr; block = (tile, headgroup of 4); wave = one head.
// ---------------------------------------------------------------------------
__global__ __launch_bounds__(256, 4) void gat_phase1(
    const float* __restrict__ x,      // [4096][256]
    const f16*   __restrict__ Wt,     // [8][64][256]
    const float* __restrict__ a,      // [8][128]
    f16*      __restrict__ h_t,
    unsigned* __restrict__ srcPK,
    f16*      __restrict__ dstE1,
    f16*      __restrict__ dstE5)
{
    __shared__ f16 xs[16][264];

    const int lane = threadIdx.x & 63;
    const int wv   = threadIdx.x >> 6;
    const int tile = blockIdx.x >> 1;
    const int hd   = (blockIdx.x & 1) * 4 + wv;
    const int r    = lane & 15;
    const int q    = lane >> 4;
    const int nb   = tile * 16;

    #pragma unroll
    for (int c = 0; c < 4; ++c) {
        int idx = c * 1024 + threadIdx.x * 4;
        int row = idx >> 8, col = idx & 255;
        float4 v = *(const float4*)(x + (size_t)(nb + row) * IN_FEAT + col);
        uint2 st = { pkh2(v.x, v.y), pkh2(v.z, v.w) };
        *(uint2*)(&xs[row][col]) = st;
    }
    __syncthreads();

    const f16* Wth = Wt + (size_t)hd * OUT_FEAT * IN_FEAT;
    f32x4 acc[4] = {};

    #pragma unroll 2
    for (int k0 = 0; k0 < IN_FEAT; k0 += 32) {
        f16x8 af = *(const f16x8*)(&xs[r][k0 + q * 8]);
        #pragma unroll
        for (int f = 0; f < 4; ++f) {
            f16x8 bf = *(const f16x8*)(Wth + (size_t)(16 * f + r) * IN_FEAT + k0 + q * 8);
            acc[f] = __builtin_amdgcn_mfma_f32_16x16x32_f16(af, bf, acc[f], 0, 0, 0);
        }
    }

    float asv[4], adv[4];
    #pragma unroll
    for (int f = 0; f < 4; ++f) {
        asv[f] = a[hd * 128 + 16 * f + r];
        adv[f] = a[hd * 128 + 64 + 16 * f + r];
    }
    float sp[4], dp[4];
    #pragma unroll
    for (int reg = 0; reg < 4; ++reg) {
        sp[reg] = acc[0][reg] * asv[0] + acc[1][reg] * asv[1]
                + acc[2][reg] * asv[2] + acc[3][reg] * asv[3];
        dp[reg] = acc[0][reg] * adv[0] + acc[1][reg] * adv[1]
                + acc[2][reg] * adv[2] + acc[3][reg] * adv[3];
    }
    #pragma unroll
    for (int m = 1; m <= 8; m <<= 1) {
        #pragma unroll
        for (int reg = 0; reg < 4; ++reg) {
            sp[reg] += __shfl_xor(sp[reg], m);
            dp[reg] += __shfl_xor(dp[reg], m);
        }
    }

    #pragma unroll
    for (int f = 0; f < 4; ++f) {
        uint2 st = { pkh2(acc[f][0], acc[f][1]), pkh2(acc[f][2], acc[f][3]) };
        *(uint2*)(h_t + (size_t)(hd * OUT_FEAT + 16 * f + r) * N_NODES + nb + 4 * q) = st;
    }

    if (r == 0) {
        #pragma unroll
        for (int reg = 0; reg < 4; ++reg) {
            int row = nb + 4 * q + reg;
            float s = sp[reg] * LOG2E;
            float d = dp[reg] * LOG2E;
            srcPK[hd * N_NODES + row] = pkh2(exp2f(s), exp2f(0.2f * s));
            dstE1[hd * N_NODES + row] = (f16)exp2f(d);
            dstE5[hd * N_NODES + row] = (f16)exp2f(0.2f * d);
        }
    }
}

// ---------------------------------------------------------------------------
// Phase 2: grid = 2048 blocks, 256 thr (4 waves, wave = 32 rows).
// Index map: hd = bi>>8, rowgrp = (bi>>3)&31, chunk = bi&7 (mlen=512).
//  - chunk == bi mod 8 == XCD (round-robin): each XCD touches ONE 2 MB emask
//    column slice + its h_t/dstE slices -> all L2-resident, emask fetched
//    from HBM exactly once device-wide (r10 bug: 69 MB refetch).
//  - 2048 blocks = 8 blocks/CU = 32 waves/CU: 8 independent barrier domains
//    overlap each other's drain stalls (replaces r11's register prefetch,
//    which corrupted results — reverted to r10's proven in-loop loads).
// ---------------------------------------------------------------------------
__global__ __launch_bounds__(256, 4) void gat_phase2p(
    const f16* __restrict__ h_t,
    const unsigned* __restrict__ srcPK,
    const f16* __restrict__ dstE1,
    const f16* __restrict__ dstE5,
    const unsigned char* __restrict__ emask8,
    float* __restrict__ numA,
    float* __restrict__ denA)
{
    __shared__ f16 Vs[2][64 * 32];   // [buf][feat][m] 4 KB each

    const int lane = threadIdx.x & 63;
    const int wv   = threadIdx.x >> 6;     // 0..3
    const int r    = lane & 15;
    const int q    = lane >> 4;
    const int q8   = q * 8;

    const int hd     = blockIdx.x >> 8;          // 0..7
    const int rowgrp = (blockIdx.x >> 3) & 31;   // 0..31
    const int chunk  = blockIdx.x & 7;           // 0..7 == XCD
    const int n0     = rowgrp * 128 + wv * 32;
    const int mbase  = chunk * 512;

    HU s0u, s1u;
    s0u.u = srcPK[hd * N_NODES + n0 + r];
    s1u.u = srcPK[hd * N_NODES + n0 + 16 + r];
    const f16x2 se1_0 = { s0u.h[0], s0u.h[0] };
    const f16x2 se5_0 = { s0u.h[1], s0u.h[1] };
    const f16x2 se1_1 = { s1u.h[0], s1u.h[0] };
    const f16x2 se5_1 = { s1u.h[1], s1u.h[1] };

    const f16* e1p = dstE1 + (size_t)hd * N_NODES + mbase;
    const f16* e5p = dstE5 + (size_t)hd * N_NODES + mbase;
    const unsigned char* em0 = emask8 + (size_t)(n0 + r)      * N_NODES + mbase;
    const unsigned char* em1 = emask8 + (size_t)(n0 + 16 + r) * N_NODES + mbase;

    // staging: 4 waves x 16 feat-rows; lane -> (feat = 16wv + lane>>2, m-oct)
    const f16* Vhead = h_t + (size_t)hd * OUT_FEAT * N_NODES + mbase;
    const f16* sbase = Vhead + (size_t)(16 * wv + (lane >> 2)) * N_NODES
                             + (lane & 3) * 8;

    f32x4 acc0 = {}, acc1 = {}, acc2 = {}, acc3 = {}, accD0 = {};
    f32x4 acc4 = {}, acc5 = {}, acc6 = {}, acc7 = {}, accD1 = {};
    f16x8 ones;
    #pragma unroll
    for (int j = 0; j < 8; ++j) ones[j] = (f16)1.0f;

    async_copy16(sbase, &Vs[0][16 * wv * 32]);

    for (int it = 0; it < 16; ++it) {
        const int cur = it & 1;
        __syncthreads();   // drains staged V for buf[cur]

        {
            int nit = (it + 1) & 15;   // wrap: harmless reload on last iter
            async_copy16(sbase + nit * 32, &Vs[1 - cur][16 * wv * 32]);
        }

        uint4 e1v = *(const uint4*)(e1p + it * 32 + q8);   // 8 f16 E1d
        uint4 e5v = *(const uint4*)(e5p + it * 32 + q8);   // 8 f16 E5d
        uint2 m0v = *(const uint2*)(em0 + it * 32 + q8);   // 8 mask bytes
        uint2 m1v = *(const uint2*)(em1 + it * 32 + q8);

        unsigned e1d[4] = {e1v.x, e1v.y, e1v.z, e1v.w};
        unsigned e5d[4] = {e5v.x, e5v.y, e5v.z, e5v.w};
        unsigned mk0[4], mk1[4];
        mk0[0] = __builtin_amdgcn_perm(0u, m0v.x, 0x01010000u);
        mk0[1] = __builtin_amdgcn_perm(0u, m0v.x, 0x03030202u);
        mk0[2] = __builtin_amdgcn_perm(0u, m0v.y, 0x01010000u);
        mk0[3] = __builtin_amdgcn_perm(0u, m0v.y, 0x03030202u);
        mk1[0] = __builtin_amdgcn_perm(0u, m1v.x, 0x01010000u);
        mk1[1] = __builtin_amdgcn_perm(0u, m1v.x, 0x03030202u);
        mk1[2] = __builtin_amdgcn_perm(0u, m1v.y, 0x01010000u);
        mk1[3] = __builtin_amdgcn_perm(0u, m1v.y, 0x03030202u);

        A8 A0, A1;
        #pragma unroll
        for (int jp = 0; jp < 4; ++jp) {
            HU ed1; ed1.u = e1d[jp];
            HU ed5; ed5.u = e5d[jp];
            HU w0, w1;
            w0.h = __builtin_elementwise_max(se1_0 * ed1.h, se5_0 * ed5.h);
            w1.h = __builtin_elementwise_max(se1_1 * ed1.h, se5_1 * ed5.h);
            A0.u[jp] = w0.u & mk0[jp];
            A1.u[jp] = w1.u & mk1[jp];
        }

        f16x8 b0 = *(const f16x8*)(&Vs[cur][(     r) * 32 + q8]);
        f16x8 b1 = *(const f16x8*)(&Vs[cur][(16 + r) * 32 + q8]);
        f16x8 b2 = *(const f16x8*)(&Vs[cur][(32 + r) * 32 + q8]);
        f16x8 b3 = *(const f16x8*)(&Vs[cur][(48 + r) * 32 + q8]);

        acc0  = __builtin_amdgcn_mfma_f32_16x16x32_f16(A0.v, b0,   acc0,  0, 0, 0);
        acc1  = __builtin_amdgcn_mfma_f32_16x16x32_f16(A0.v, b1,   acc1,  0, 0, 0);
        acc2  = __builtin_amdgcn_mfma_f32_16x16x32_f16(A0.v, b2,   acc2,  0, 0, 0);
        acc3  = __builtin_amdgcn_mfma_f32_16x16x32_f16(A0.v, b3,   acc3,  0, 0, 0);
        accD0 = __builtin_amdgcn_mfma_f32_16x16x32_f16(A0.v, ones, accD0, 0, 0, 0);
        acc4  = __builtin_amdgcn_mfma_f32_16x16x32_f16(A1.v, b0,   acc4,  0, 0, 0);
        acc5  = __builtin_amdgcn_mfma_f32_16x16x32_f16(A1.v, b1,   acc5,  0, 0, 0);
        acc6  = __builtin_amdgcn_mfma_f32_16x16x32_f16(A1.v, b2,   acc6,  0, 0, 0);
        acc7  = __builtin_amdgcn_mfma_f32_16x16x32_f16(A1.v, b3,   acc7,  0, 0, 0);
        accD1 = __builtin_amdgcn_mfma_f32_16x16x32_f16(A1.v, ones, accD1, 0, 0, 0);
    }

    #pragma unroll
    for (int reg = 0; reg < 4; ++reg) {
        int row0 = n0 + 4 * q + reg;
        int row1 = row0 + 16;
        atomicAdd(&numA[((size_t)row0 * NHEAD + hd) * 64 +  0 + r], acc0[reg]);
        atomicAdd(&numA[((size_t)row0 * NHEAD + hd) * 64 + 16 + r], acc1[reg]);
        atomicAdd(&numA[((size_t)row0 * NHEAD + hd) * 64 + 32 + r], acc2[reg]);
        atomicAdd(&numA[((size_t)row0 * NHEAD + hd) * 64 + 48 + r], acc3[reg]);
        atomicAdd(&numA[((size_t)row1 * NHEAD + hd) * 64 +  0 + r], acc4[reg]);
        atomicAdd(&numA[((size_t)row1 * NHEAD + hd) * 64 + 16 + r], acc5[reg]);
        atomicAdd(&numA[((size_t)row1 * NHEAD + hd) * 64 + 32 + r], acc6[reg]);
        atomicAdd(&numA[((size_t)row1 * NHEAD + hd) * 64 + 48 + r], acc7[reg]);
        if (r == 0) {
            atomicAdd(&denA[(size_t)row0 * NHEAD + hd], accD0[reg]);
            atomicAdd(&denA[(size_t)row1 * NHEAD + hd], accD1[reg]);
        }
    }
}

// ---------------------------------------------------------------------------
// Combine: divide, mean over heads, ELU. 256 blocks x 512 thr (2 cols/thr).
// ---------------------------------------------------------------------------
__global__ __launch_bounds__(512) void gat_combine(
    const float* __restrict__ numA,
    const float* __restrict__ denA,
    float* __restrict__ out)
{
    int gid = blockIdx.x * 512 + threadIdx.x;   // 0..131071
    int row = gid >> 5;
    int cp  = (gid & 31) * 2;
    float s0 = 0.f, s1 = 0.f;
    #pragma unroll
    for (int h = 0; h < NHEAD; ++h) {
        float2 v = *(const float2*)(numA + ((size_t)row * NHEAD + h) * 64 + cp);
        float inv = 1.f / denA[(size_t)row * NHEAD + h];
        s0 += v.x * inv;
        s1 += v.y * inv;
    }
    s0 *= 0.125f; s1 *= 0.125f;
    float e0 = s0 > 0.f ? s0 : expm1f(s0);
    float e1 = s1 > 0.f ? s1 : expm1f(s1);
    float2 pk = {e0, e1};
    *(float2*)(out + (size_t)row * OUT_FEAT + cp) = pk;
}

// ---------------------------------------------------------------------------
extern "C" void kernel_launch(void* const* d_in, const int* in_sizes, int n_in,
                              void* d_out, int out_size, void* d_ws, size_t ws_size,
                              hipStream_t stream)
{
    const float* x   = (const float*)d_in[0];
    const int*   adj = (const int*)d_in[1];
    const float* W   = (const float*)d_in[2];
    const float* a   = (const float*)d_in[3];
    float* out = (float*)d_out;

    char* ws = (char*)d_ws;
    f16*           h_t   = (f16*)ws;
    unsigned*      srcPK = (unsigned*)(ws + OFF_SRCPK);
    f16*           dstE1 = (f16*)(ws + OFF_DSTE1);
    f16*           dstE5 = (f16*)(ws + OFF_DSTE5);
    f16*           Wt    = (f16*)(ws + OFF_WT);
    unsigned char* em    = (unsigned char*)(ws + OFF_EM);
    float*         numA  = (float*)(ws + OFF_NUMA);
    float*         denA  = (float*)(ws + OFF_DENA);

    gat_pack   <<<2128, 256, 0, stream>>>(adj, (unsigned*)em, W, Wt, numA);
    gat_phase1 <<<512,  256, 0, stream>>>(x, Wt, a, h_t, srcPK, dstE1, dstE5);
    gat_phase2p<<<2048, 256, 0, stream>>>(h_t, srcPK, dstE1, dstE5, em, numA, denA);
    gat_combine<<<256,  512, 0, stream>>>(numA, denA, out);
}

// Round 13
// 184.602 us; speedup vs baseline: 1.1108x; 1.1108x over previous
//
#include <hip/hip_runtime.h>
#include <hip/hip_fp16.h>
#include <cstdint>

#define N_NODES 4096
#define IN_FEAT 256
#define OUT_FEAT 64
#define NHEAD 8
#define LOG2E 1.4426950408889634f

typedef _Float16 f16;
typedef f16   f16x2 __attribute__((ext_vector_type(2)));
typedef f16   f16x8 __attribute__((ext_vector_type(8)));
typedef float f32x4 __attribute__((ext_vector_type(4)));

// ws layout (bytes) — total 30,015,488 (< 38.8 MB proven in r3):
//   h_t   @ 0        : 8*64*4096*2 = 4194304   f16 [h][feat][node]
//   srcPK @ 4194304  : 8*4096*4    = 131072    dword {E1s,E5s} f16 pair per (h,n)
//   dstE1 @ 4325376  : 8*4096*2    = 65536     f16 exp2(t_d) per (h,m)
//   dstE5 @ 4390912  : 8*4096*2    = 65536     f16 exp2(0.2 t_d)
//   Wt    @ 4456448  : 8*64*256*2  = 262144    f16 [h][col][k]
//   emask @ 4718592  : 4096*4096   = 16777216  byte 0xFF/0x00 = adj!=0
//   numA  @ 21495808 : 4096*8*64*4 = 8388608   f32 atomic accumulators
//   denA  @ 29884416 : 4096*8*4    = 131072
#define OFF_SRCPK 4194304
#define OFF_DSTE1 4325376
#define OFF_DSTE5 4390912
#define OFF_WT    4456448
#define OFF_EM    4718592
#define OFF_NUMA  21495808ULL
#define OFF_DENA  29884416ULL

union HU { unsigned u; f16x2 h; };
union A8 { f16x8 v; unsigned u[4]; };

__device__ __forceinline__ void async_copy16(const void* g, void* l) {
    __builtin_amdgcn_global_load_lds(
        (const __attribute__((address_space(1))) void*)g,
        (__attribute__((address_space(3))) void*)l, 16, 0, 0);
}

static __device__ inline unsigned pkh2(float a, float b) {
    union { f16 h[2]; unsigned u; } t;
    t.h[0] = (f16)a; t.h[1] = (f16)b; return t.u;
}

// ---------------------------------------------------------------------------
// Pack kernel, 3 branches by blockIdx:
//   [0,1024)      adj -> emask bytes (elementwise, fully coalesced, no atomics)
//   [1024,1088)   prepack Wt[hd][col][k] = f16 W[hd][k][col]
//   [1088,2128)   zero numA/denA
// ---------------------------------------------------------------------------
__global__ __launch_bounds__(256) void gat_pack(
    const int* __restrict__ adj, unsigned* __restrict__ em32,
    const float* __restrict__ W, f16* __restrict__ Wt,
    float* __restrict__ zeroBase)
{
    if (blockIdx.x >= 1088) {   // zero branch: 1040 blocks x 2048 floats
        size_t off = ((size_t)(blockIdx.x - 1088) * 256 + threadIdx.x) * 8;
        float4 z = {0.f, 0.f, 0.f, 0.f};
        *(float4*)(zeroBase + off)     = z;
        *(float4*)(zeroBase + off + 4) = z;
        return;
    }
    if (blockIdx.x >= 1024) {   // prepack branch
        int gid = (blockIdx.x - 1024) * 256 + threadIdx.x;   // 0..16383
        int hd  = gid >> 11;
        int rem = gid & 2047;
        int c   = rem >> 5;
        int kg  = rem & 31;
        const float* src = W + ((size_t)hd * IN_FEAT + kg * 8) * OUT_FEAT + c;
        f16x8 v;
        #pragma unroll
        for (int t = 0; t < 8; ++t) v[t] = (f16)src[(size_t)t * OUT_FEAT];
        *(f16x8*)(Wt + ((size_t)hd * OUT_FEAT + c) * IN_FEAT + kg * 8) = v;
        return;
    }

    // emask branch: wave per row, 16 steps of int4->4 mask bytes (1 dword)
    const int wv   = threadIdx.x >> 6;
    const int lane = threadIdx.x & 63;
    const int row  = blockIdx.x * 4 + wv;
    const int* p   = adj + (size_t)row * N_NODES;
    unsigned* dst  = em32 + (size_t)row * (N_NODES / 4);
    #pragma unroll 4
    for (int s = 0; s < 16; ++s) {
        int4 v = *(const int4*)(p + s * 256 + lane * 4);
        unsigned d = (v.x ? 0x000000FFu : 0u) | (v.y ? 0x0000FF00u : 0u)
                   | (v.z ? 0x00FF0000u : 0u) | (v.w ? 0xFF000000u : 0u);
        dst[s * 64 + lane] = d;
    }
}

// ---------------------------------------------------------------------------
// Phase 1: h = x @ W[h] (f16 MFMA). Epilogue stores factored exponentials.
// 512 blocks x 256 thr; block = (tile, headgroup of 4); wave = one head.
// ---------------------------------------------------------------------------
__global__ __launch_bounds__(256, 4) void gat_phase1(
    const float* __restrict__ x,      // [4096][256]
    const f16*   __restrict__ Wt,     // [8][64][256]
    const float* __restrict__ a,      // [8][128]
    f16*      __restrict__ h_t,
    unsigned* __restrict__ srcPK,
    f16*      __restrict__ dstE1,
    f16*      __restrict__ dstE5)
{
    __shared__ f16 xs[16][264];

    const int lane = threadIdx.x & 63;
    const int wv   = threadIdx.x >> 6;
    const int tile = blockIdx.x >> 1;
    const int hd   = (blockIdx.x & 1) * 4 + wv;
    const int r    = lane & 15;
    const int q    = lane >> 4;
    const int nb   = tile * 16;

    #pragma unroll
    for (int c = 0; c < 4; ++c) {
        int idx = c * 1024 + threadIdx.x * 4;
        int row = idx >> 8, col = idx & 255;
        float4 v = *(const float4*)(x + (size_t)(nb + row) * IN_FEAT + col);
        uint2 st = { pkh2(v.x, v.y), pkh2(v.z, v.w) };
        *(uint2*)(&xs[row][col]) = st;
    }
    __syncthreads();

    const f16* Wth = Wt + (size_t)hd * OUT_FEAT * IN_FEAT;
    f32x4 acc[4] = {};

    #pragma unroll 2
    for (int k0 = 0; k0 < IN_FEAT; k0 += 32) {
        f16x8 af = *(const f16x8*)(&xs[r][k0 + q * 8]);
        #pragma unroll
        for (int f = 0; f < 4; ++f) {
            f16x8 bf = *(const f16x8*)(Wth + (size_t)(16 * f + r) * IN_FEAT + k0 + q * 8);
            acc[f] = __builtin_amdgcn_mfma_f32_16x16x32_f16(af, bf, acc[f], 0, 0, 0);
        }
    }

    float asv[4], adv[4];
    #pragma unroll
    for (int f = 0; f < 4; ++f) {
        asv[f] = a[hd * 128 + 16 * f + r];
        adv[f] = a[hd * 128 + 64 + 16 * f + r];
    }
    float sp[4], dp[4];
    #pragma unroll
    for (int reg = 0; reg < 4; ++reg) {
        sp[reg] = acc[0][reg] * asv[0] + acc[1][reg] * asv[1]
                + acc[2][reg] * asv[2] + acc[3][reg] * asv[3];
        dp[reg] = acc[0][reg] * adv[0] + acc[1][reg] * adv[1]
                + acc[2][reg] * adv[2] + acc[3][reg] * adv[3];
    }
    #pragma unroll
    for (int m = 1; m <= 8; m <<= 1) {
        #pragma unroll
        for (int reg = 0; reg < 4; ++reg) {
            sp[reg] += __shfl_xor(sp[reg], m);
            dp[reg] += __shfl_xor(dp[reg], m);
        }
    }

    #pragma unroll
    for (int f = 0; f < 4; ++f) {
        uint2 st = { pkh2(acc[f][0], acc[f][1]), pkh2(acc[f][2], acc[f][3]) };
        *(uint2*)(h_t + (size_t)(hd * OUT_FEAT + 16 * f + r) * N_NODES + nb + 4 * q) = st;
    }

    if (r == 0) {
        #pragma unroll
        for (int reg = 0; reg < 4; ++reg) {
            int row = nb + 4 * q + reg;
            float s = sp[reg] * LOG2E;
            float d = dp[reg] * LOG2E;
            srcPK[hd * N_NODES + row] = pkh2(exp2f(s), exp2f(0.2f * s));
            dstE1[hd * N_NODES + row] = (f16)exp2f(d);
            dstE5[hd * N_NODES + row] = (f16)exp2f(0.2f * d);
        }
    }
}

// ---------------------------------------------------------------------------
// Phase 2: grid = 1024 blocks, 256 thr (4 waves, wave = 32 rows).
// Decode: hd = bi>>7, rowgrp = (bi>>2)&31, chunk = bi&3 (mlen=1024).
// XCD = bi&7 = chunk | (rowgrp&1)<<2:
//  - the 8 head-blocks sharing one emask slice differ by multiples of 128
//    (bits 7..9) == 0 mod 8 -> same XCD -> per-XCD emask slice = 16 rowgrps
//    x 128 rows x 1024 m = 2 MB, L2-resident (r12 proved: FETCH 69->10.8 MB)
//  - 4 chunks (not r12's 8): atomic epilogue volume back to ~33 MB
//    (r12's 64 MB of HBM atomic RMW cost +16 us).
// Body identical to the r10-verified kernel (in-loop operand loads; r11's
// cross-barrier register prefetch corrupted results and stays dead).
// ---------------------------------------------------------------------------
__global__ __launch_bounds__(256, 4) void gat_phase2p(
    const f16* __restrict__ h_t,
    const unsigned* __restrict__ srcPK,
    const f16* __restrict__ dstE1,
    const f16* __restrict__ dstE5,
    const unsigned char* __restrict__ emask8,
    float* __restrict__ numA,
    float* __restrict__ denA)
{
    __shared__ f16 Vs[2][64 * 32];   // [buf][feat][m] 4 KB each

    const int lane = threadIdx.x & 63;
    const int wv   = threadIdx.x >> 6;     // 0..3
    const int r    = lane & 15;
    const int q    = lane >> 4;
    const int q8   = q * 8;

    const int hd     = blockIdx.x >> 7;          // 0..7
    const int rowgrp = (blockIdx.x >> 2) & 31;   // 0..31
    const int chunk  = blockIdx.x & 3;           // 0..3
    const int n0     = rowgrp * 128 + wv * 32;
    const int mbase  = chunk * 1024;

    HU s0u, s1u;
    s0u.u = srcPK[hd * N_NODES + n0 + r];
    s1u.u = srcPK[hd * N_NODES + n0 + 16 + r];
    const f16x2 se1_0 = { s0u.h[0], s0u.h[0] };
    const f16x2 se5_0 = { s0u.h[1], s0u.h[1] };
    const f16x2 se1_1 = { s1u.h[0], s1u.h[0] };
    const f16x2 se5_1 = { s1u.h[1], s1u.h[1] };

    const f16* e1p = dstE1 + (size_t)hd * N_NODES + mbase;
    const f16* e5p = dstE5 + (size_t)hd * N_NODES + mbase;
    const unsigned char* em0 = emask8 + (size_t)(n0 + r)      * N_NODES + mbase;
    const unsigned char* em1 = emask8 + (size_t)(n0 + 16 + r) * N_NODES + mbase;

    // staging: 4 waves x 16 feat-rows; lane -> (feat = 16wv + lane>>2, m-oct)
    const f16* Vhead = h_t + (size_t)hd * OUT_FEAT * N_NODES + mbase;
    const f16* sbase = Vhead + (size_t)(16 * wv + (lane >> 2)) * N_NODES
                             + (lane & 3) * 8;

    f32x4 acc0 = {}, acc1 = {}, acc2 = {}, acc3 = {}, accD0 = {};
    f32x4 acc4 = {}, acc5 = {}, acc6 = {}, acc7 = {}, accD1 = {};
    f16x8 ones;
    #pragma unroll
    for (int j = 0; j < 8; ++j) ones[j] = (f16)1.0f;

    async_copy16(sbase, &Vs[0][16 * wv * 32]);

    for (int it = 0; it < 32; ++it) {
        const int cur = it & 1;
        __syncthreads();   // drains staged V for buf[cur]

        {
            int nit = (it + 1) & 31;   // wrap: harmless reload on last iter
            async_copy16(sbase + nit * 32, &Vs[1 - cur][16 * wv * 32]);
        }

        uint4 e1v = *(const uint4*)(e1p + it * 32 + q8);   // 8 f16 E1d
        uint4 e5v = *(const uint4*)(e5p + it * 32 + q8);   // 8 f16 E5d
        uint2 m0v = *(const uint2*)(em0 + it * 32 + q8);   // 8 mask bytes
        uint2 m1v = *(const uint2*)(em1 + it * 32 + q8);

        unsigned e1d[4] = {e1v.x, e1v.y, e1v.z, e1v.w};
        unsigned e5d[4] = {e5v.x, e5v.y, e5v.z, e5v.w};
        unsigned mk0[4], mk1[4];
        mk0[0] = __builtin_amdgcn_perm(0u, m0v.x, 0x01010000u);
        mk0[1] = __builtin_amdgcn_perm(0u, m0v.x, 0x03030202u);
        mk0[2] = __builtin_amdgcn_perm(0u, m0v.y, 0x01010000u);
        mk0[3] = __builtin_amdgcn_perm(0u, m0v.y, 0x03030202u);
        mk1[0] = __builtin_amdgcn_perm(0u, m1v.x, 0x01010000u);
        mk1[1] = __builtin_amdgcn_perm(0u, m1v.x, 0x03030202u);
        mk1[2] = __builtin_amdgcn_perm(0u, m1v.y, 0x01010000u);
        mk1[3] = __builtin_amdgcn_perm(0u, m1v.y, 0x03030202u);

        A8 A0, A1;
        #pragma unroll
        for (int jp = 0; jp < 4; ++jp) {
            HU ed1; ed1.u = e1d[jp];
            HU ed5; ed5.u = e5d[jp];
            HU w0, w1;
            w0.h = __builtin_elementwise_max(se1_0 * ed1.h, se5_0 * ed5.h);
            w1.h = __builtin_elementwise_max(se1_1 * ed1.h, se5_1 * ed5.h);
            A0.u[jp] = w0.u & mk0[jp];
            A1.u[jp] = w1.u & mk1[jp];
        }

        f16x8 b0 = *(const f16x8*)(&Vs[cur][(     r) * 32 + q8]);
        f16x8 b1 = *(const f16x8*)(&Vs[cur][(16 + r) * 32 + q8]);
        f16x8 b2 = *(const f16x8*)(&Vs[cur][(32 + r) * 32 + q8]);
        f16x8 b3 = *(const f16x8*)(&Vs[cur][(48 + r) * 32 + q8]);

        acc0  = __builtin_amdgcn_mfma_f32_16x16x32_f16(A0.v, b0,   acc0,  0, 0, 0);
        acc1  = __builtin_amdgcn_mfma_f32_16x16x32_f16(A0.v, b1,   acc1,  0, 0, 0);
        acc2  = __builtin_amdgcn_mfma_f32_16x16x32_f16(A0.v, b2,   acc2,  0, 0, 0);
        acc3  = __builtin_amdgcn_mfma_f32_16x16x32_f16(A0.v, b3,   acc3,  0, 0, 0);
        accD0 = __builtin_amdgcn_mfma_f32_16x16x32_f16(A0.v, ones, accD0, 0, 0, 0);
        acc4  = __builtin_amdgcn_mfma_f32_16x16x32_f16(A1.v, b0,   acc4,  0, 0, 0);
        acc5  = __builtin_amdgcn_mfma_f32_16x16x32_f16(A1.v, b1,   acc5,  0, 0, 0);
        acc6  = __builtin_amdgcn_mfma_f32_16x16x32_f16(A1.v, b2,   acc6,  0, 0, 0);
        acc7  = __builtin_amdgcn_mfma_f32_16x16x32_f16(A1.v, b3,   acc7,  0, 0, 0);
        accD1 = __builtin_amdgcn_mfma_f32_16x16x32_f16(A1.v, ones, accD1, 0, 0, 0);
    }

    #pragma unroll
    for (int reg = 0; reg < 4; ++reg) {
        int row0 = n0 + 4 * q + reg;
        int row1 = row0 + 16;
        atomicAdd(&numA[((size_t)row0 * NHEAD + hd) * 64 +  0 + r], acc0[reg]);
        atomicAdd(&numA[((size_t)row0 * NHEAD + hd) * 64 + 16 + r], acc1[reg]);
        atomicAdd(&numA[((size_t)row0 * NHEAD + hd) * 64 + 32 + r], acc2[reg]);
        atomicAdd(&numA[((size_t)row0 * NHEAD + hd) * 64 + 48 + r], acc3[reg]);
        atomicAdd(&numA[((size_t)row1 * NHEAD + hd) * 64 +  0 + r], acc4[reg]);
        atomicAdd(&numA[((size_t)row1 * NHEAD + hd) * 64 + 16 + r], acc5[reg]);
        atomicAdd(&numA[((size_t)row1 * NHEAD + hd) * 64 + 32 + r], acc6[reg]);
        atomicAdd(&numA[((size_t)row1 * NHEAD + hd) * 64 + 48 + r], acc7[reg]);
        if (r == 0) {
            atomicAdd(&denA[(size_t)row0 * NHEAD + hd], accD0[reg]);
            atomicAdd(&denA[(size_t)row1 * NHEAD + hd], accD1[reg]);
        }
    }
}

// ---------------------------------------------------------------------------
// Combine: divide, mean over heads, ELU. 256 blocks x 512 thr (2 cols/thr).
// ---------------------------------------------------------------------------
__global__ __launch_bounds__(512) void gat_combine(
    const float* __restrict__ numA,
    const float* __restrict__ denA,
    float* __restrict__ out)
{
    int gid = blockIdx.x * 512 + threadIdx.x;   // 0..131071
    int row = gid >> 5;
    int cp  = (gid & 31) * 2;
    float s0 = 0.f, s1 = 0.f;
    #pragma unroll
    for (int h = 0; h < NHEAD; ++h) {
        float2 v = *(const float2*)(numA + ((size_t)row * NHEAD + h) * 64 + cp);
        float inv = 1.f / denA[(size_t)row * NHEAD + h];
        s0 += v.x * inv;
        s1 += v.y * inv;
    }
    s0 *= 0.125f; s1 *= 0.125f;
    float e0 = s0 > 0.f ? s0 : expm1f(s0);
    float e1 = s1 > 0.f ? s1 : expm1f(s1);
    float2 pk = {e0, e1};
    *(float2*)(out + (size_t)row * OUT_FEAT + cp) = pk;
}

// ---------------------------------------------------------------------------
extern "C" void kernel_launch(void* const* d_in, const int* in_sizes, int n_in,
                              void* d_out, int out_size, void* d_ws, size_t ws_size,
                              hipStream_t stream)
{
    const float* x   = (const float*)d_in[0];
    const int*   adj = (const int*)d_in[1];
    const float* W   = (const float*)d_in[2];
    const float* a   = (const float*)d_in[3];
    float* out = (float*)d_out;

    char* ws = (char*)d_ws;
    f16*           h_t   = (f16*)ws;
    unsigned*      srcPK = (unsigned*)(ws + OFF_SRCPK);
    f16*           dstE1 = (f16*)(ws + OFF_DSTE1);
    f16*           dstE5 = (f16*)(ws + OFF_DSTE5);
    f16*           Wt    = (f16*)(ws + OFF_WT);
    unsigned char* em    = (unsigned char*)(ws + OFF_EM);
    float*         numA  = (float*)(ws + OFF_NUMA);
    float*         denA  = (float*)(ws + OFF_DENA);

    gat_pack   <<<2128, 256, 0, stream>>>(adj, (unsigned*)em, W, Wt, numA);
    gat_phase1 <<<512,  256, 0, stream>>>(x, Wt, a, h_t, srcPK, dstE1, dstE5);
    gat_phase2p<<<1024, 256, 0, stream>>>(h_t, srcPK, dstE1, dstE5, em, numA, denA);
    gat_combine<<<256,  512, 0, stream>>>(numA, denA, out);
}

// Round 14
// 175.031 us; speedup vs baseline: 1.1716x; 1.0547x over previous
//
#include <hip/hip_runtime.h>
#include <hip/hip_fp16.h>
#include <cstdint>

#define N_NODES 4096
#define IN_FEAT 256
#define OUT_FEAT 64
#define NHEAD 8
#define LOG2E 1.4426950408889634f

typedef _Float16 f16;
typedef f16   f16x2 __attribute__((ext_vector_type(2)));
typedef f16   f16x8 __attribute__((ext_vector_type(8)));
typedef float f32x4 __attribute__((ext_vector_type(4)));

// ws layout (bytes) — total 30,015,488 (< 38.8 MB proven in r3):
//   h_t   @ 0        : 8*64*4096*2 = 4194304   f16 [h][feat][node]
//   srcPK @ 4194304  : 8*4096*4    = 131072    dword {E1s,E5s} f16 pair per (h,n)
//   dstE1 @ 4325376  : 8*4096*2    = 65536     f16 exp2(t_d) per (h,m)
//   dstE5 @ 4390912  : 8*4096*2    = 65536     f16 exp2(0.2 t_d)
//   Wt    @ 4456448  : 8*64*256*2  = 262144    f16 [h][col][k]
//   emask @ 4718592  : 4096*4096   = 16777216  byte 0xFF/0x00 = adj!=0
//   numA  @ 21495808 : 4096*8*64*4 = 8388608   f32 atomic accumulators
//   denA  @ 29884416 : 4096*8*4    = 131072
#define OFF_SRCPK 4194304
#define OFF_DSTE1 4325376
#define OFF_DSTE5 4390912
#define OFF_WT    4456448
#define OFF_EM    4718592
#define OFF_NUMA  21495808ULL
#define OFF_DENA  29884416ULL

union HU { unsigned u; f16x2 h; };
union A8 { f16x8 v; unsigned u[4]; };

__device__ __forceinline__ void async_copy16(const void* g, void* l) {
    __builtin_amdgcn_global_load_lds(
        (const __attribute__((address_space(1))) void*)g,
        (__attribute__((address_space(3))) void*)l, 16, 0, 0);
}

static __device__ inline unsigned pkh2(float a, float b) {
    union { f16 h[2]; unsigned u; } t;
    t.h[0] = (f16)a; t.h[1] = (f16)b; return t.u;
}

// ---------------------------------------------------------------------------
// Pack kernel, 3 branches by blockIdx:
//   [0,1024)      adj -> emask bytes (elementwise, fully coalesced, no atomics)
//   [1024,1088)   prepack Wt[hd][col][k] = f16 W[hd][k][col]
//   [1088,2128)   zero numA/denA
// ---------------------------------------------------------------------------
__global__ __launch_bounds__(256) void gat_pack(
    const int* __restrict__ adj, unsigned* __restrict__ em32,
    const float* __restrict__ W, f16* __restrict__ Wt,
    float* __restrict__ zeroBase)
{
    if (blockIdx.x >= 1088) {   // zero branch: 1040 blocks x 2048 floats
        size_t off = ((size_t)(blockIdx.x - 1088) * 256 + threadIdx.x) * 8;
        float4 z = {0.f, 0.f, 0.f, 0.f};
        *(float4*)(zeroBase + off)     = z;
        *(float4*)(zeroBase + off + 4) = z;
        return;
    }
    if (blockIdx.x >= 1024) {   // prepack branch
        int gid = (blockIdx.x - 1024) * 256 + threadIdx.x;   // 0..16383
        int hd  = gid >> 11;
        int rem = gid & 2047;
        int c   = rem >> 5;
        int kg  = rem & 31;
        const float* src = W + ((size_t)hd * IN_FEAT + kg * 8) * OUT_FEAT + c;
        f16x8 v;
        #pragma unroll
        for (int t = 0; t < 8; ++t) v[t] = (f16)src[(size_t)t * OUT_FEAT];
        *(f16x8*)(Wt + ((size_t)hd * OUT_FEAT + c) * IN_FEAT + kg * 8) = v;
        return;
    }

    // emask branch: wave per row, 16 steps of int4->4 mask bytes (1 dword)
    const int wv   = threadIdx.x >> 6;
    const int lane = threadIdx.x & 63;
    const int row  = blockIdx.x * 4 + wv;
    const int* p   = adj + (size_t)row * N_NODES;
    unsigned* dst  = em32 + (size_t)row * (N_NODES / 4);
    #pragma unroll 4
    for (int s = 0; s < 16; ++s) {
        int4 v = *(const int4*)(p + s * 256 + lane * 4);
        unsigned d = (v.x ? 0x000000FFu : 0u) | (v.y ? 0x0000FF00u : 0u)
                   | (v.z ? 0x00FF0000u : 0u) | (v.w ? 0xFF000000u : 0u);
        dst[s * 64 + lane] = d;
    }
}

// ---------------------------------------------------------------------------
// Phase 1: h = x @ W[h] (f16 MFMA). Epilogue stores factored exponentials.
// 512 blocks x 256 thr; block = (tile, headgroup of 4); wave = one head.
// ---------------------------------------------------------------------------
__global__ __launch_bounds__(256, 4) void gat_phase1(
    const float* __restrict__ x,      // [4096][256]
    const f16*   __restrict__ Wt,     // [8][64][256]
    const float* __restrict__ a,      // [8][128]
    f16*      __restrict__ h_t,
    unsigned* __restrict__ srcPK,
    f16*      __restrict__ dstE1,
    f16*      __restrict__ dstE5)
{
    __shared__ f16 xs[16][264];

    const int lane = threadIdx.x & 63;
    const int wv   = threadIdx.x >> 6;
    const int tile = blockIdx.x >> 1;
    const int hd   = (blockIdx.x & 1) * 4 + wv;
    const int r    = lane & 15;
    const int q    = lane >> 4;
    const int nb   = tile * 16;

    #pragma unroll
    for (int c = 0; c < 4; ++c) {
        int idx = c * 1024 + threadIdx.x * 4;
        int row = idx >> 8, col = idx & 255;
        float4 v = *(const float4*)(x + (size_t)(nb + row) * IN_FEAT + col);
        uint2 st = { pkh2(v.x, v.y), pkh2(v.z, v.w) };
        *(uint2*)(&xs[row][col]) = st;
    }
    __syncthreads();

    const f16* Wth = Wt + (size_t)hd * OUT_FEAT * IN_FEAT;
    f32x4 acc[4] = {};

    #pragma unroll 2
    for (int k0 = 0; k0 < IN_FEAT; k0 += 32) {
        f16x8 af = *(const f16x8*)(&xs[r][k0 + q * 8]);
        #pragma unroll
        for (int f = 0; f < 4; ++f) {
            f16x8 bf = *(const f16x8*)(Wth + (size_t)(16 * f + r) * IN_FEAT + k0 + q * 8);
            acc[f] = __builtin_amdgcn_mfma_f32_16x16x32_f16(af, bf, acc[f], 0, 0, 0);
        }
    }

    float asv[4], adv[4];
    #pragma unroll
    for (int f = 0; f < 4; ++f) {
        asv[f] = a[hd * 128 + 16 * f + r];
        adv[f] = a[hd * 128 + 64 + 16 * f + r];
    }
    float sp[4], dp[4];
    #pragma unroll
    for (int reg = 0; reg < 4; ++reg) {
        sp[reg] = acc[0][reg] * asv[0] + acc[1][reg] * asv[1]
                + acc[2][reg] * asv[2] + acc[3][reg] * asv[3];
        dp[reg] = acc[0][reg] * adv[0] + acc[1][reg] * adv[1]
                + acc[2][reg] * adv[2] + acc[3][reg] * adv[3];
    }
    #pragma unroll
    for (int m = 1; m <= 8; m <<= 1) {
        #pragma unroll
        for (int reg = 0; reg < 4; ++reg) {
            sp[reg] += __shfl_xor(sp[reg], m);
            dp[reg] += __shfl_xor(dp[reg], m);
        }
    }

    #pragma unroll
    for (int f = 0; f < 4; ++f) {
        uint2 st = { pkh2(acc[f][0], acc[f][1]), pkh2(acc[f][2], acc[f][3]) };
        *(uint2*)(h_t + (size_t)(hd * OUT_FEAT + 16 * f + r) * N_NODES + nb + 4 * q) = st;
    }

    if (r == 0) {
        #pragma unroll
        for (int reg = 0; reg < 4; ++reg) {
            int row = nb + 4 * q + reg;
            float s = sp[reg] * LOG2E;
            float d = dp[reg] * LOG2E;
            srcPK[hd * N_NODES + row] = pkh2(exp2f(s), exp2f(0.2f * s));
            dstE1[hd * N_NODES + row] = (f16)exp2f(d);
            dstE5[hd * N_NODES + row] = (f16)exp2f(0.2f * d);
        }
    }
}

// ---------------------------------------------------------------------------
// Phase 2: grid = 1024 blocks, 256 thr (4 waves, wave = 32 rows).
// Decode (r13, proven): hd = bi>>7, rowgrp = (bi>>2)&31, chunk = bi&3.
// NEW (r14): ALL in-loop operands ride the double-buffered global_load_lds
// pipeline — V tile (8 KB), e1/e5 tiles (64 B each), emask tile (4 KB).
// The K-loop contains ZERO global loads; r13's exposed L2 latency on the
// post-barrier operand loads (compiler can't hoist across __syncthreads)
// is removed. LDS/buf f16 idx: V [0,4096) [feat][m32]; e1 [4096,4128);
// e5 [4128,4160); em [4160,6208) as [row128][16] (2x8B halves).
// ---------------------------------------------------------------------------
__global__ __launch_bounds__(256, 4) void gat_phase2p(
    const f16* __restrict__ h_t,
    const unsigned* __restrict__ srcPK,
    const f16* __restrict__ dstE1,
    const f16* __restrict__ dstE5,
    const unsigned char* __restrict__ emask8,
    float* __restrict__ numA,
    float* __restrict__ denA)
{
    __shared__ f16 Vbuf[2][6208];   // 12416 B per buffer

    const int t    = threadIdx.x;
    const int lane = t & 63;
    const int wv   = t >> 6;       // 0..3
    const int r    = lane & 15;
    const int q    = lane >> 4;
    const int q8   = q * 8;

    const int hd     = blockIdx.x >> 7;          // 0..7
    const int rowgrp = (blockIdx.x >> 2) & 31;   // 0..31
    const int chunk  = blockIdx.x & 3;           // 0..3
    const int nblk   = rowgrp * 128;
    const int n0     = nblk + wv * 32;
    const int mbase  = chunk * 1024;

    HU s0u, s1u;
    s0u.u = srcPK[hd * N_NODES + n0 + r];
    s1u.u = srcPK[hd * N_NODES + n0 + 16 + r];
    const f16x2 se1_0 = { s0u.h[0], s0u.h[0] };
    const f16x2 se5_0 = { s0u.h[1], s0u.h[1] };
    const f16x2 se1_1 = { s1u.h[0], s1u.h[0] };
    const f16x2 se5_1 = { s1u.h[1], s1u.h[1] };

    // per-thread staging sources (advance by it*32 f16 / it*32 bytes per iter)
    const f16* Vhead = h_t + (size_t)hd * OUT_FEAT * N_NODES + mbase;
    const f16* srcV  = Vhead + (size_t)(t >> 2) * N_NODES + (t & 3) * 8;
    const unsigned char* srcM =
        emask8 + (size_t)(nblk + (t >> 1)) * N_NODES + mbase + (t & 1) * 16;
    const f16* esrc = (t < 4) ? (dstE1 + (size_t)hd * N_NODES + mbase + t * 8)
                              : (dstE5 + (size_t)hd * N_NODES + mbase + (t - 4) * 8);

    f32x4 acc0 = {}, acc1 = {}, acc2 = {}, acc3 = {}, accD0 = {};
    f32x4 acc4 = {}, acc5 = {}, acc6 = {}, acc7 = {}, accD1 = {};
    f16x8 ones;
    #pragma unroll
    for (int j = 0; j < 8; ++j) ones[j] = (f16)1.0f;

    // prologue: stage it=0 into buf 0  (V; emask; e1/e5 from 8 lanes of wave 0
    //   — LDS dests are base + lane*16 contiguous per copy, per the
    //   global_load_lds wave-uniform-base constraint)
    async_copy16(srcV, &Vbuf[0][t * 8]);
    async_copy16(srcM, &Vbuf[0][4160 + t * 8]);
    if (t < 8) async_copy16(esrc, &Vbuf[0][4096 + t * 8]);

    for (int it = 0; it < 32; ++it) {
        const int cur = it & 1;
        __syncthreads();   // drains staged loads for buf[cur]

        {
            const int nit = (it + 1) & 31;   // wrap: harmless reload
            async_copy16(srcV + nit * 32, &Vbuf[1 - cur][t * 8]);
            async_copy16(srcM + nit * 32, &Vbuf[1 - cur][4160 + t * 8]);
            if (t < 8) async_copy16(esrc + nit * 32, &Vbuf[1 - cur][4096 + t * 8]);
        }

        // operands — all from LDS now (e reads broadcast; em reads b64-optimal)
        uint4 e1v = *(const uint4*)(&Vbuf[cur][4096 + q8]);
        uint4 e5v = *(const uint4*)(&Vbuf[cur][4128 + q8]);
        uint2 m0v = *(const uint2*)(&Vbuf[cur][4160 + (wv * 32 + r) * 16 + q * 4]);
        uint2 m1v = *(const uint2*)(&Vbuf[cur][4160 + (wv * 32 + 16 + r) * 16 + q * 4]);

        unsigned e1d[4] = {e1v.x, e1v.y, e1v.z, e1v.w};
        unsigned e5d[4] = {e5v.x, e5v.y, e5v.z, e5v.w};
        unsigned mk0[4], mk1[4];
        mk0[0] = __builtin_amdgcn_perm(0u, m0v.x, 0x01010000u);
        mk0[1] = __builtin_amdgcn_perm(0u, m0v.x, 0x03030202u);
        mk0[2] = __builtin_amdgcn_perm(0u, m0v.y, 0x01010000u);
        mk0[3] = __builtin_amdgcn_perm(0u, m0v.y, 0x03030202u);
        mk1[0] = __builtin_amdgcn_perm(0u, m1v.x, 0x01010000u);
        mk1[1] = __builtin_amdgcn_perm(0u, m1v.x, 0x03030202u);
        mk1[2] = __builtin_amdgcn_perm(0u, m1v.y, 0x01010000u);
        mk1[3] = __builtin_amdgcn_perm(0u, m1v.y, 0x03030202u);

        A8 A0, A1;
        #pragma unroll
        for (int jp = 0; jp < 4; ++jp) {
            HU ed1; ed1.u = e1d[jp];
            HU ed5; ed5.u = e5d[jp];
            HU w0, w1;
            w0.h = __builtin_elementwise_max(se1_0 * ed1.h, se5_0 * ed5.h);
            w1.h = __builtin_elementwise_max(se1_1 * ed1.h, se5_1 * ed5.h);
            A0.u[jp] = w0.u & mk0[jp];
            A1.u[jp] = w1.u & mk1[jp];
        }

        f16x8 b0 = *(const f16x8*)(&Vbuf[cur][(     r) * 32 + q8]);
        f16x8 b1 = *(const f16x8*)(&Vbuf[cur][(16 + r) * 32 + q8]);
        f16x8 b2 = *(const f16x8*)(&Vbuf[cur][(32 + r) * 32 + q8]);
        f16x8 b3 = *(const f16x8*)(&Vbuf[cur][(48 + r) * 32 + q8]);

        acc0  = __builtin_amdgcn_mfma_f32_16x16x32_f16(A0.v, b0,   acc0,  0, 0, 0);
        acc1  = __builtin_amdgcn_mfma_f32_16x16x32_f16(A0.v, b1,   acc1,  0, 0, 0);
        acc2  = __builtin_amdgcn_mfma_f32_16x16x32_f16(A0.v, b2,   acc2,  0, 0, 0);
        acc3  = __builtin_amdgcn_mfma_f32_16x16x32_f16(A0.v, b3,   acc3,  0, 0, 0);
        accD0 = __builtin_amdgcn_mfma_f32_16x16x32_f16(A0.v, ones, accD0, 0, 0, 0);
        acc4  = __builtin_amdgcn_mfma_f32_16x16x32_f16(A1.v, b0,   acc4,  0, 0, 0);
        acc5  = __builtin_amdgcn_mfma_f32_16x16x32_f16(A1.v, b1,   acc5,  0, 0, 0);
        acc6  = __builtin_amdgcn_mfma_f32_16x16x32_f16(A1.v, b2,   acc6,  0, 0, 0);
        acc7  = __builtin_amdgcn_mfma_f32_16x16x32_f16(A1.v, b3,   acc7,  0, 0, 0);
        accD1 = __builtin_amdgcn_mfma_f32_16x16x32_f16(A1.v, ones, accD1, 0, 0, 0);
    }

    #pragma unroll
    for (int reg = 0; reg < 4; ++reg) {
        int row0 = n0 + 4 * q + reg;
        int row1 = row0 + 16;
        atomicAdd(&numA[((size_t)row0 * NHEAD + hd) * 64 +  0 + r], acc0[reg]);
        atomicAdd(&numA[((size_t)row0 * NHEAD + hd) * 64 + 16 + r], acc1[reg]);
        atomicAdd(&numA[((size_t)row0 * NHEAD + hd) * 64 + 32 + r], acc2[reg]);
        atomicAdd(&numA[((size_t)row0 * NHEAD + hd) * 64 + 48 + r], acc3[reg]);
        atomicAdd(&numA[((size_t)row1 * NHEAD + hd) * 64 +  0 + r], acc4[reg]);
        atomicAdd(&numA[((size_t)row1 * NHEAD + hd) * 64 + 16 + r], acc5[reg]);
        atomicAdd(&numA[((size_t)row1 * NHEAD + hd) * 64 + 32 + r], acc6[reg]);
        atomicAdd(&numA[((size_t)row1 * NHEAD + hd) * 64 + 48 + r], acc7[reg]);
        if (r == 0) {
            atomicAdd(&denA[(size_t)row0 * NHEAD + hd], accD0[reg]);
            atomicAdd(&denA[(size_t)row1 * NHEAD + hd], accD1[reg]);
        }
    }
}

// ---------------------------------------------------------------------------
// Combine: divide, mean over heads, ELU. 256 blocks x 512 thr (2 cols/thr).
// ---------------------------------------------------------------------------
__global__ __launch_bounds__(512) void gat_combine(
    const float* __restrict__ numA,
    const float* __restrict__ denA,
    float* __restrict__ out)
{
    int gid = blockIdx.x * 512 + threadIdx.x;   // 0..131071
    int row = gid >> 5;
    int cp  = (gid & 31) * 2;
    float s0 = 0.f, s1 = 0.f;
    #pragma unroll
    for (int h = 0; h < NHEAD; ++h) {
        float2 v = *(const float2*)(numA + ((size_t)row * NHEAD + h) * 64 + cp);
        float inv = 1.f / denA[(size_t)row * NHEAD + h];
        s0 += v.x * inv;
        s1 += v.y * inv;
    }
    s0 *= 0.125f; s1 *= 0.125f;
    float e0 = s0 > 0.f ? s0 : expm1f(s0);
    float e1 = s1 > 0.f ? s1 : expm1f(s1);
    float2 pk = {e0, e1};
    *(float2*)(out + (size_t)row * OUT_FEAT + cp) = pk;
}

// ---------------------------------------------------------------------------
extern "C" void kernel_launch(void* const* d_in, const int* in_sizes, int n_in,
                              void* d_out, int out_size, void* d_ws, size_t ws_size,
                              hipStream_t stream)
{
    const float* x   = (const float*)d_in[0];
    const int*   adj = (const int*)d_in[1];
    const float* W   = (const float*)d_in[2];
    const float* a   = (const float*)d_in[3];
    float* out = (float*)d_out;

    char* ws = (char*)d_ws;
    f16*           h_t   = (f16*)ws;
    unsigned*      srcPK = (unsigned*)(ws + OFF_SRCPK);
    f16*           dstE1 = (f16*)(ws + OFF_DSTE1);
    f16*           dstE5 = (f16*)(ws + OFF_DSTE5);
    f16*           Wt    = (f16*)(ws + OFF_WT);
    unsigned char* em    = (unsigned char*)(ws + OFF_EM);
    float*         numA  = (float*)(ws + OFF_NUMA);
    float*         denA  = (float*)(ws + OFF_DENA);

    gat_pack   <<<2128, 256, 0, stream>>>(adj, (unsigned*)em, W, Wt, numA);
    gat_phase1 <<<512,  256, 0, stream>>>(x, Wt, a, h_t, srcPK, dstE1, dstE5);
    gat_phase2p<<<1024, 256, 0, stream>>>(h_t, srcPK, dstE1, dstE5, em, numA, denA);
    gat_combine<<<256,  512, 0, stream>>>(numA, denA, out);
}

// Round 15
// 174.011 us; speedup vs baseline: 1.1784x; 1.0059x over previous
//
#include <hip/hip_runtime.h>
#include <hip/hip_fp16.h>
#include <cstdint>

#define N_NODES 4096
#define IN_FEAT 256
#define OUT_FEAT 64
#define NHEAD 8
#define LOG2E 1.4426950408889634f

typedef _Float16 f16;
typedef f16   f16x2 __attribute__((ext_vector_type(2)));
typedef f16   f16x8 __attribute__((ext_vector_type(8)));
typedef float f32x4 __attribute__((ext_vector_type(4)));

// ws layout (bytes) — total 30,015,488 (< 38.8 MB proven in r3):
//   h_t   @ 0        : 8*64*4096*2 = 4194304   f16 [h][feat][node]
//   srcPK @ 4194304  : 8*4096*4    = 131072    dword {E1s,E5s} f16 pair per (h,n)
//   dstE1 @ 4325376  : 8*4096*2    = 65536     f16 exp2(t_d) per (h,m)
//   dstE5 @ 4390912  : 8*4096*2    = 65536     f16 exp2(0.2 t_d)
//   Wt    @ 4456448  : 8*64*256*2  = 262144    f16 [h][col][k]
//   emask @ 4718592  : 4096*4096   = 16777216  byte 0xFF/0x00 = adj!=0
//   numA  @ 21495808 : 4096*8*64*4 = 8388608   f32 atomic accumulators
//   denA  @ 29884416 : 4096*8*4    = 131072
#define OFF_SRCPK 4194304
#define OFF_DSTE1 4325376
#define OFF_DSTE5 4390912
#define OFF_WT    4456448
#define OFF_EM    4718592
#define OFF_NUMA  21495808ULL
#define OFF_DENA  29884416ULL

union HU { unsigned u; f16x2 h; };
union A8 { f16x8 v; unsigned u[4]; };

__device__ __forceinline__ void async_copy16(const void* g, void* l) {
    __builtin_amdgcn_global_load_lds(
        (const __attribute__((address_space(1))) void*)g,
        (__attribute__((address_space(3))) void*)l, 16, 0, 0);
}

static __device__ inline unsigned pkh2(float a, float b) {
    union { f16 h[2]; unsigned u; } t;
    t.h[0] = (f16)a; t.h[1] = (f16)b; return t.u;
}

// ---------------------------------------------------------------------------
// Pack kernel, 3 branches by blockIdx:
//   [0,1024)      adj -> emask bytes (elementwise, fully coalesced, no atomics)
//   [1024,1088)   prepack Wt[hd][col][k] = f16 W[hd][k][col]
//   [1088,2128)   zero numA/denA
// ---------------------------------------------------------------------------
__global__ __launch_bounds__(256) void gat_pack(
    const int* __restrict__ adj, unsigned* __restrict__ em32,
    const float* __restrict__ W, f16* __restrict__ Wt,
    float* __restrict__ zeroBase)
{
    if (blockIdx.x >= 1088) {   // zero branch: 1040 blocks x 2048 floats
        size_t off = ((size_t)(blockIdx.x - 1088) * 256 + threadIdx.x) * 8;
        float4 z = {0.f, 0.f, 0.f, 0.f};
        *(float4*)(zeroBase + off)     = z;
        *(float4*)(zeroBase + off + 4) = z;
        return;
    }
    if (blockIdx.x >= 1024) {   // prepack branch
        int gid = (blockIdx.x - 1024) * 256 + threadIdx.x;   // 0..16383
        int hd  = gid >> 11;
        int rem = gid & 2047;
        int c   = rem >> 5;
        int kg  = rem & 31;
        const float* src = W + ((size_t)hd * IN_FEAT + kg * 8) * OUT_FEAT + c;
        f16x8 v;
        #pragma unroll
        for (int t = 0; t < 8; ++t) v[t] = (f16)src[(size_t)t * OUT_FEAT];
        *(f16x8*)(Wt + ((size_t)hd * OUT_FEAT + c) * IN_FEAT + kg * 8) = v;
        return;
    }

    // emask branch: wave per row, 16 steps of int4->4 mask bytes (1 dword)
    const int wv   = threadIdx.x >> 6;
    const int lane = threadIdx.x & 63;
    const int row  = blockIdx.x * 4 + wv;
    const int* p   = adj + (size_t)row * N_NODES;
    unsigned* dst  = em32 + (size_t)row * (N_NODES / 4);
    #pragma unroll 4
    for (int s = 0; s < 16; ++s) {
        int4 v = *(const int4*)(p + s * 256 + lane * 4);
        unsigned d = (v.x ? 0x000000FFu : 0u) | (v.y ? 0x0000FF00u : 0u)
                   | (v.z ? 0x00FF0000u : 0u) | (v.w ? 0xFF000000u : 0u);
        dst[s * 64 + lane] = d;
    }
}

// ---------------------------------------------------------------------------
// Phase 1: h = x @ W[h] (f16 MFMA). Epilogue stores factored exponentials.
// 512 blocks x 256 thr; block = (tile, headgroup of 4); wave = one head.
// ---------------------------------------------------------------------------
__global__ __launch_bounds__(256, 4) void gat_phase1(
    const float* __restrict__ x,      // [4096][256]
    const f16*   __restrict__ Wt,     // [8][64][256]
    const float* __restrict__ a,      // [8][128]
    f16*      __restrict__ h_t,
    unsigned* __restrict__ srcPK,
    f16*      __restrict__ dstE1,
    f16*      __restrict__ dstE5)
{
    __shared__ f16 xs[16][264];

    const int lane = threadIdx.x & 63;
    const int wv   = threadIdx.x >> 6;
    const int tile = blockIdx.x >> 1;
    const int hd   = (blockIdx.x & 1) * 4 + wv;
    const int r    = lane & 15;
    const int q    = lane >> 4;
    const int nb   = tile * 16;

    #pragma unroll
    for (int c = 0; c < 4; ++c) {
        int idx = c * 1024 + threadIdx.x * 4;
        int row = idx >> 8, col = idx & 255;
        float4 v = *(const float4*)(x + (size_t)(nb + row) * IN_FEAT + col);
        uint2 st = { pkh2(v.x, v.y), pkh2(v.z, v.w) };
        *(uint2*)(&xs[row][col]) = st;
    }
    __syncthreads();

    const f16* Wth = Wt + (size_t)hd * OUT_FEAT * IN_FEAT;
    f32x4 acc[4] = {};

    #pragma unroll 2
    for (int k0 = 0; k0 < IN_FEAT; k0 += 32) {
        f16x8 af = *(const f16x8*)(&xs[r][k0 + q * 8]);
        #pragma unroll
        for (int f = 0; f < 4; ++f) {
            f16x8 bf = *(const f16x8*)(Wth + (size_t)(16 * f + r) * IN_FEAT + k0 + q * 8);
            acc[f] = __builtin_amdgcn_mfma_f32_16x16x32_f16(af, bf, acc[f], 0, 0, 0);
        }
    }

    float asv[4], adv[4];
    #pragma unroll
    for (int f = 0; f < 4; ++f) {
        asv[f] = a[hd * 128 + 16 * f + r];
        adv[f] = a[hd * 128 + 64 + 16 * f + r];
    }
    float sp[4], dp[4];
    #pragma unroll
    for (int reg = 0; reg < 4; ++reg) {
        sp[reg] = acc[0][reg] * asv[0] + acc[1][reg] * asv[1]
                + acc[2][reg] * asv[2] + acc[3][reg] * asv[3];
        dp[reg] = acc[0][reg] * adv[0] + acc[1][reg] * adv[1]
                + acc[2][reg] * adv[2] + acc[3][reg] * adv[3];
    }
    #pragma unroll
    for (int m = 1; m <= 8; m <<= 1) {
        #pragma unroll
        for (int reg = 0; reg < 4; ++reg) {
            sp[reg] += __shfl_xor(sp[reg], m);
            dp[reg] += __shfl_xor(dp[reg], m);
        }
    }

    #pragma unroll
    for (int f = 0; f < 4; ++f) {
        uint2 st = { pkh2(acc[f][0], acc[f][1]), pkh2(acc[f][2], acc[f][3]) };
        *(uint2*)(h_t + (size_t)(hd * OUT_FEAT + 16 * f + r) * N_NODES + nb + 4 * q) = st;
    }

    if (r == 0) {
        #pragma unroll
        for (int reg = 0; reg < 4; ++reg) {
            int row = nb + 4 * q + reg;
            float s = sp[reg] * LOG2E;
            float d = dp[reg] * LOG2E;
            srcPK[hd * N_NODES + row] = pkh2(exp2f(s), exp2f(0.2f * s));
            dstE1[hd * N_NODES + row] = (f16)exp2f(d);
            dstE5[hd * N_NODES + row] = (f16)exp2f(0.2f * d);
        }
    }
}

// ---------------------------------------------------------------------------
// Phase 2: grid = 1024 blocks, 256 thr (4 waves, wave = 32 rows).
// r15 decode: hd = bi>>7, chunk = (bi>>5)&3, rowgrp = bi&31.
//   XCD = bi&7 = rowgrp&7 -> ALL blocks sharing a rowgrp (8 heads x 4
//   chunks) land on ONE XCD: numA atomic targets, emask rows and srcPK rows
//   are XCD-local. r14's decode put the 4 chunk-blocks of one numA row-set
//   on 4 different XCDs -> every epilogue atomic was a cross-XCD RMW
//   (WRITE_SIZE 36.9 MB = 4.4x numA size). Cost: h_t/dstE (m-major) now
//   read by all 8 XCDs (~+36 MB streamed FETCH, hidden by DMA pipeline).
// Body identical to r14 (proven): all operands ride the double-buffered
// global_load_lds pipeline; zero global loads in the K-loop.
// ---------------------------------------------------------------------------
__global__ __launch_bounds__(256, 4) void gat_phase2p(
    const f16* __restrict__ h_t,
    const unsigned* __restrict__ srcPK,
    const f16* __restrict__ dstE1,
    const f16* __restrict__ dstE5,
    const unsigned char* __restrict__ emask8,
    float* __restrict__ numA,
    float* __restrict__ denA)
{
    __shared__ f16 Vbuf[2][6208];   // 12416 B per buffer

    const int t    = threadIdx.x;
    const int lane = t & 63;
    const int wv   = t >> 6;       // 0..3
    const int r    = lane & 15;
    const int q    = lane >> 4;
    const int q8   = q * 8;

    const int hd     = blockIdx.x >> 7;          // 0..7
    const int chunk  = (blockIdx.x >> 5) & 3;    // 0..3
    const int rowgrp = blockIdx.x & 31;          // 0..31  (XCD = rowgrp&7)
    const int nblk   = rowgrp * 128;
    const int n0     = nblk + wv * 32;
    const int mbase  = chunk * 1024;

    HU s0u, s1u;
    s0u.u = srcPK[hd * N_NODES + n0 + r];
    s1u.u = srcPK[hd * N_NODES + n0 + 16 + r];
    const f16x2 se1_0 = { s0u.h[0], s0u.h[0] };
    const f16x2 se5_0 = { s0u.h[1], s0u.h[1] };
    const f16x2 se1_1 = { s1u.h[0], s1u.h[0] };
    const f16x2 se5_1 = { s1u.h[1], s1u.h[1] };

    // per-thread staging sources (advance by it*32 f16 / it*32 bytes per iter)
    const f16* Vhead = h_t + (size_t)hd * OUT_FEAT * N_NODES + mbase;
    const f16* srcV  = Vhead + (size_t)(t >> 2) * N_NODES + (t & 3) * 8;
    const unsigned char* srcM =
        emask8 + (size_t)(nblk + (t >> 1)) * N_NODES + mbase + (t & 1) * 16;
    const f16* esrc = (t < 4) ? (dstE1 + (size_t)hd * N_NODES + mbase + t * 8)
                              : (dstE5 + (size_t)hd * N_NODES + mbase + (t - 4) * 8);

    f32x4 acc0 = {}, acc1 = {}, acc2 = {}, acc3 = {}, accD0 = {};
    f32x4 acc4 = {}, acc5 = {}, acc6 = {}, acc7 = {}, accD1 = {};
    f16x8 ones;
    #pragma unroll
    for (int j = 0; j < 8; ++j) ones[j] = (f16)1.0f;

    // prologue: stage it=0 into buf 0
    async_copy16(srcV, &Vbuf[0][t * 8]);
    async_copy16(srcM, &Vbuf[0][4160 + t * 8]);
    if (t < 8) async_copy16(esrc, &Vbuf[0][4096 + t * 8]);

    for (int it = 0; it < 32; ++it) {
        const int cur = it & 1;
        __syncthreads();   // drains staged loads for buf[cur]

        {
            const int nit = (it + 1) & 31;   // wrap: harmless reload
            async_copy16(srcV + nit * 32, &Vbuf[1 - cur][t * 8]);
            async_copy16(srcM + nit * 32, &Vbuf[1 - cur][4160 + t * 8]);
            if (t < 8) async_copy16(esrc + nit * 32, &Vbuf[1 - cur][4096 + t * 8]);
        }

        // operands — all from LDS (e reads broadcast; em reads b64-optimal)
        uint4 e1v = *(const uint4*)(&Vbuf[cur][4096 + q8]);
        uint4 e5v = *(const uint4*)(&Vbuf[cur][4128 + q8]);
        uint2 m0v = *(const uint2*)(&Vbuf[cur][4160 + (wv * 32 + r) * 16 + q * 4]);
        uint2 m1v = *(const uint2*)(&Vbuf[cur][4160 + (wv * 32 + 16 + r) * 16 + q * 4]);

        unsigned e1d[4] = {e1v.x, e1v.y, e1v.z, e1v.w};
        unsigned e5d[4] = {e5v.x, e5v.y, e5v.z, e5v.w};
        unsigned mk0[4], mk1[4];
        mk0[0] = __builtin_amdgcn_perm(0u, m0v.x, 0x01010000u);
        mk0[1] = __builtin_amdgcn_perm(0u, m0v.x, 0x03030202u);
        mk0[2] = __builtin_amdgcn_perm(0u, m0v.y, 0x01010000u);
        mk0[3] = __builtin_amdgcn_perm(0u, m0v.y, 0x03030202u);
        mk1[0] = __builtin_amdgcn_perm(0u, m1v.x, 0x01010000u);
        mk1[1] = __builtin_amdgcn_perm(0u, m1v.x, 0x03030202u);
        mk1[2] = __builtin_amdgcn_perm(0u, m1v.y, 0x01010000u);
        mk1[3] = __builtin_amdgcn_perm(0u, m1v.y, 0x03030202u);

        A8 A0, A1;
        #pragma unroll
        for (int jp = 0; jp < 4; ++jp) {
            HU ed1; ed1.u = e1d[jp];
            HU ed5; ed5.u = e5d[jp];
            HU w0, w1;
            w0.h = __builtin_elementwise_max(se1_0 * ed1.h, se5_0 * ed5.h);
            w1.h = __builtin_elementwise_max(se1_1 * ed1.h, se5_1 * ed5.h);
            A0.u[jp] = w0.u & mk0[jp];
            A1.u[jp] = w1.u & mk1[jp];
        }

        f16x8 b0 = *(const f16x8*)(&Vbuf[cur][(     r) * 32 + q8]);
        f16x8 b1 = *(const f16x8*)(&Vbuf[cur][(16 + r) * 32 + q8]);
        f16x8 b2 = *(const f16x8*)(&Vbuf[cur][(32 + r) * 32 + q8]);
        f16x8 b3 = *(const f16x8*)(&Vbuf[cur][(48 + r) * 32 + q8]);

        acc0  = __builtin_amdgcn_mfma_f32_16x16x32_f16(A0.v, b0,   acc0,  0, 0, 0);
        acc1  = __builtin_amdgcn_mfma_f32_16x16x32_f16(A0.v, b1,   acc1,  0, 0, 0);
        acc2  = __builtin_amdgcn_mfma_f32_16x16x32_f16(A0.v, b2,   acc2,  0, 0, 0);
        acc3  = __builtin_amdgcn_mfma_f32_16x16x32_f16(A0.v, b3,   acc3,  0, 0, 0);
        accD0 = __builtin_amdgcn_mfma_f32_16x16x32_f16(A0.v, ones, accD0, 0, 0, 0);
        acc4  = __builtin_amdgcn_mfma_f32_16x16x32_f16(A1.v, b0,   acc4,  0, 0, 0);
        acc5  = __builtin_amdgcn_mfma_f32_16x16x32_f16(A1.v, b1,   acc5,  0, 0, 0);
        acc6  = __builtin_amdgcn_mfma_f32_16x16x32_f16(A1.v, b2,   acc6,  0, 0, 0);
        acc7  = __builtin_amdgcn_mfma_f32_16x16x32_f16(A1.v, b3,   acc7,  0, 0, 0);
        accD1 = __builtin_amdgcn_mfma_f32_16x16x32_f16(A1.v, ones, accD1, 0, 0, 0);
    }

    #pragma unroll
    for (int reg = 0; reg < 4; ++reg) {
        int row0 = n0 + 4 * q + reg;
        int row1 = row0 + 16;
        atomicAdd(&numA[((size_t)row0 * NHEAD + hd) * 64 +  0 + r], acc0[reg]);
        atomicAdd(&numA[((size_t)row0 * NHEAD + hd) * 64 + 16 + r], acc1[reg]);
        atomicAdd(&numA[((size_t)row0 * NHEAD + hd) * 64 + 32 + r], acc2[reg]);
        atomicAdd(&numA[((size_t)row0 * NHEAD + hd) * 64 + 48 + r], acc3[reg]);
        atomicAdd(&numA[((size_t)row1 * NHEAD + hd) * 64 +  0 + r], acc4[reg]);
        atomicAdd(&numA[((size_t)row1 * NHEAD + hd) * 64 + 16 + r], acc5[reg]);
        atomicAdd(&numA[((size_t)row1 * NHEAD + hd) * 64 + 32 + r], acc6[reg]);
        atomicAdd(&numA[((size_t)row1 * NHEAD + hd) * 64 + 48 + r], acc7[reg]);
        if (r == 0) {
            atomicAdd(&denA[(size_t)row0 * NHEAD + hd], accD0[reg]);
            atomicAdd(&denA[(size_t)row1 * NHEAD + hd], accD1[reg]);
        }
    }
}

// ---------------------------------------------------------------------------
// Combine: divide, mean over heads, ELU. 256 blocks x 512 thr (2 cols/thr).
// ---------------------------------------------------------------------------
__global__ __launch_bounds__(512) void gat_combine(
    const float* __restrict__ numA,
    const float* __restrict__ denA,
    float* __restrict__ out)
{
    int gid = blockIdx.x * 512 + threadIdx.x;   // 0..131071
    int row = gid >> 5;
    int cp  = (gid & 31) * 2;
    float s0 = 0.f, s1 = 0.f;
    #pragma unroll
    for (int h = 0; h < NHEAD; ++h) {
        float2 v = *(const float2*)(numA + ((size_t)row * NHEAD + h) * 64 + cp);
        float inv = 1.f / denA[(size_t)row * NHEAD + h];
        s0 += v.x * inv;
        s1 += v.y * inv;
    }
    s0 *= 0.125f; s1 *= 0.125f;
    float e0 = s0 > 0.f ? s0 : expm1f(s0);
    float e1 = s1 > 0.f ? s1 : expm1f(s1);
    float2 pk = {e0, e1};
    *(float2*)(out + (size_t)row * OUT_FEAT + cp) = pk;
}

// ---------------------------------------------------------------------------
extern "C" void kernel_launch(void* const* d_in, const int* in_sizes, int n_in,
                              void* d_out, int out_size, void* d_ws, size_t ws_size,
                              hipStream_t stream)
{
    const float* x   = (const float*)d_in[0];
    const int*   adj = (const int*)d_in[1];
    const float* W   = (const float*)d_in[2];
    const float* a   = (const float*)d_in[3];
    float* out = (float*)d_out;

    char* ws = (char*)d_ws;
    f16*           h_t   = (f16*)ws;
    unsigned*      srcPK = (unsigned*)(ws + OFF_SRCPK);
    f16*           dstE1 = (f16*)(ws + OFF_DSTE1);
    f16*           dstE5 = (f16*)(ws + OFF_DSTE5);
    f16*           Wt    = (f16*)(ws + OFF_WT);
    unsigned char* em    = (unsigned char*)(ws + OFF_EM);
    float*         numA  = (float*)(ws + OFF_NUMA);
    float*         denA  = (float*)(ws + OFF_DENA);

    gat_pack   <<<2128, 256, 0, stream>>>(adj, (unsigned*)em, W, Wt, numA);
    gat_phase1 <<<512,  256, 0, stream>>>(x, Wt, a, h_t, srcPK, dstE1, dstE5);
    gat_phase2p<<<1024, 256, 0, stream>>>(h_t, srcPK, dstE1, dstE5, em, numA, denA);
    gat_combine<<<256,  512, 0, stream>>>(numA, denA, out);
}

// Round 16
// 172.093 us; speedup vs baseline: 1.1916x; 1.0111x over previous
//
#include <hip/hip_runtime.h>
#include <hip/hip_fp16.h>
#include <cstdint>

#define N_NODES 4096
#define IN_FEAT 256
#define OUT_FEAT 64
#define NHEAD 8
#define LOG2E 1.4426950408889634f

typedef _Float16 f16;
typedef f16   f16x2 __attribute__((ext_vector_type(2)));
typedef f16   f16x8 __attribute__((ext_vector_type(8)));
typedef float f32x4 __attribute__((ext_vector_type(4)));

// ws layout (bytes) — total 30,015,488 (< 38.8 MB proven in r3):
//   h_t   @ 0        : 8*64*4096*2 = 4194304   f16 [h][feat][node]
//   srcPK @ 4194304  : 8*4096*4    = 131072    dword {E1s,E5s} f16 pair per (h,n)
//   dstE1 @ 4325376  : 8*4096*2    = 65536     f16 exp2(t_d) per (h,m)
//   dstE5 @ 4390912  : 8*4096*2    = 65536     f16 exp2(0.2 t_d)
//   Wt    @ 4456448  : 8*64*256*2  = 262144    f16 [h][col][k]
//   emask @ 4718592  : 4096*4096   = 16777216  byte 0xFF/0x00 = adj!=0
//   numA  @ 21495808 : 4096*8*64*4 = 8388608   f32 atomic accumulators
//   denA  @ 29884416 : 4096*8*4    = 131072
#define OFF_SRCPK 4194304
#define OFF_DSTE1 4325376
#define OFF_DSTE5 4390912
#define OFF_WT    4456448
#define OFF_EM    4718592
#define OFF_NUMA  21495808ULL
#define OFF_DENA  29884416ULL

union HU { unsigned u; f16x2 h; };
union A8 { f16x8 v; unsigned u[4]; };

__device__ __forceinline__ void async_copy16(const void* g, void* l) {
    __builtin_amdgcn_global_load_lds(
        (const __attribute__((address_space(1))) void*)g,
        (__attribute__((address_space(3))) void*)l, 16, 0, 0);
}

static __device__ inline unsigned pkh2(float a, float b) {
    union { f16 h[2]; unsigned u; } t;
    t.h[0] = (f16)a; t.h[1] = (f16)b; return t.u;
}

// ---------------------------------------------------------------------------
// Pack kernel, 3 branches by blockIdx:
//   [0,1024)      adj -> emask bytes (elementwise, fully coalesced, no atomics)
//   [1024,1088)   prepack Wt[hd][col][k] = f16 W[hd][k][col]
//   [1088,2128)   zero numA/denA
// ---------------------------------------------------------------------------
__global__ __launch_bounds__(256) void gat_pack(
    const int* __restrict__ adj, unsigned* __restrict__ em32,
    const float* __restrict__ W, f16* __restrict__ Wt,
    float* __restrict__ zeroBase)
{
    if (blockIdx.x >= 1088) {   // zero branch: 1040 blocks x 2048 floats
        size_t off = ((size_t)(blockIdx.x - 1088) * 256 + threadIdx.x) * 8;
        float4 z = {0.f, 0.f, 0.f, 0.f};
        *(float4*)(zeroBase + off)     = z;
        *(float4*)(zeroBase + off + 4) = z;
        return;
    }
    if (blockIdx.x >= 1024) {   // prepack branch
        int gid = (blockIdx.x - 1024) * 256 + threadIdx.x;   // 0..16383
        int hd  = gid >> 11;
        int rem = gid & 2047;
        int c   = rem >> 5;
        int kg  = rem & 31;
        const float* src = W + ((size_t)hd * IN_FEAT + kg * 8) * OUT_FEAT + c;
        f16x8 v;
        #pragma unroll
        for (int t = 0; t < 8; ++t) v[t] = (f16)src[(size_t)t * OUT_FEAT];
        *(f16x8*)(Wt + ((size_t)hd * OUT_FEAT + c) * IN_FEAT + kg * 8) = v;
        return;
    }

    // emask branch: wave per row, 16 steps of int4->4 mask bytes (1 dword)
    const int wv   = threadIdx.x >> 6;
    const int lane = threadIdx.x & 63;
    const int row  = blockIdx.x * 4 + wv;
    const int* p   = adj + (size_t)row * N_NODES;
    unsigned* dst  = em32 + (size_t)row * (N_NODES / 4);
    #pragma unroll 4
    for (int s = 0; s < 16; ++s) {
        int4 v = *(const int4*)(p + s * 256 + lane * 4);
        unsigned d = (v.x ? 0x000000FFu : 0u) | (v.y ? 0x0000FF00u : 0u)
                   | (v.z ? 0x00FF0000u : 0u) | (v.w ? 0xFF000000u : 0u);
        dst[s * 64 + lane] = d;
    }
}

// ---------------------------------------------------------------------------
// Phase 1: h = x @ W[h] (f16 MFMA). Epilogue stores factored exponentials.
// 512 blocks x 256 thr; block = (tile, headgroup of 4); wave = one head.
// ---------------------------------------------------------------------------
__global__ __launch_bounds__(256, 4) void gat_phase1(
    const float* __restrict__ x,      // [4096][256]
    const f16*   __restrict__ Wt,     // [8][64][256]
    const float* __restrict__ a,      // [8][128]
    f16*      __restrict__ h_t,
    unsigned* __restrict__ srcPK,
    f16*      __restrict__ dstE1,
    f16*      __restrict__ dstE5)
{
    __shared__ f16 xs[16][264];

    const int lane = threadIdx.x & 63;
    const int wv   = threadIdx.x >> 6;
    const int tile = blockIdx.x >> 1;
    const int hd   = (blockIdx.x & 1) * 4 + wv;
    const int r    = lane & 15;
    const int q    = lane >> 4;
    const int nb   = tile * 16;

    #pragma unroll
    for (int c = 0; c < 4; ++c) {
        int idx = c * 1024 + threadIdx.x * 4;
        int row = idx >> 8, col = idx & 255;
        float4 v = *(const float4*)(x + (size_t)(nb + row) * IN_FEAT + col);
        uint2 st = { pkh2(v.x, v.y), pkh2(v.z, v.w) };
        *(uint2*)(&xs[row][col]) = st;
    }
    __syncthreads();

    const f16* Wth = Wt + (size_t)hd * OUT_FEAT * IN_FEAT;
    f32x4 acc[4] = {};

    #pragma unroll 2
    for (int k0 = 0; k0 < IN_FEAT; k0 += 32) {
        f16x8 af = *(const f16x8*)(&xs[r][k0 + q * 8]);
        #pragma unroll
        for (int f = 0; f < 4; ++f) {
            f16x8 bf = *(const f16x8*)(Wth + (size_t)(16 * f + r) * IN_FEAT + k0 + q * 8);
            acc[f] = __builtin_amdgcn_mfma_f32_16x16x32_f16(af, bf, acc[f], 0, 0, 0);
        }
    }

    float asv[4], adv[4];
    #pragma unroll
    for (int f = 0; f < 4; ++f) {
        asv[f] = a[hd * 128 + 16 * f + r];
        adv[f] = a[hd * 128 + 64 + 16 * f + r];
    }
    float sp[4], dp[4];
    #pragma unroll
    for (int reg = 0; reg < 4; ++reg) {
        sp[reg] = acc[0][reg] * asv[0] + acc[1][reg] * asv[1]
                + acc[2][reg] * asv[2] + acc[3][reg] * asv[3];
        dp[reg] = acc[0][reg] * adv[0] + acc[1][reg] * adv[1]
                + acc[2][reg] * adv[2] + acc[3][reg] * adv[3];
    }
    #pragma unroll
    for (int m = 1; m <= 8; m <<= 1) {
        #pragma unroll
        for (int reg = 0; reg < 4; ++reg) {
            sp[reg] += __shfl_xor(sp[reg], m);
            dp[reg] += __shfl_xor(dp[reg], m);
        }
    }

    #pragma unroll
    for (int f = 0; f < 4; ++f) {
        uint2 st = { pkh2(acc[f][0], acc[f][1]), pkh2(acc[f][2], acc[f][3]) };
        *(uint2*)(h_t + (size_t)(hd * OUT_FEAT + 16 * f + r) * N_NODES + nb + 4 * q) = st;
    }

    if (r == 0) {
        #pragma unroll
        for (int reg = 0; reg < 4; ++reg) {
            int row = nb + 4 * q + reg;
            float s = sp[reg] * LOG2E;
            float d = dp[reg] * LOG2E;
            srcPK[hd * N_NODES + row] = pkh2(exp2f(s), exp2f(0.2f * s));
            dstE1[hd * N_NODES + row] = (f16)exp2f(d);
            dstE5[hd * N_NODES + row] = (f16)exp2f(0.2f * d);
        }
    }
}

// ---------------------------------------------------------------------------
// Phase 2: grid = 1024 blocks, 256 thr (4 waves, wave = 32 rows).
// Decode reverted to r14 (proven best 60.0us / FETCH 13.8 MB):
//   hd = bi>>7, rowgrp = (bi>>2)&31, chunk = bi&3.
// r16 change: 64-m tiles, 16 iterations — HALVED barrier count. r14/r15
// showed per-barrier overhead (~2us x 32: vmcnt(0) drain convoy across the
// 4 in-phase blocks/CU) dominates; amortize it. LDS keeps r14's bank
// pattern: each 64-m buffer = two side-by-side 32-m sub-tiles (a naive
// 64-stride V layout would be 16-way bank-conflicted).
// WRITE ~37 MB is structural (r15 falsified the placement theory:
// device-scope atomics resolve memory-side regardless of XCD).
// Buffer f16 layout: V [0,4096) = s0 [0,2048) | s1 [2048,4096), each
// [feat][m32]; em [4096,8192) = s0|s1, each [row128][16]; e [8192,8320)
// = {e1 s0, e5 s0, e1 s1, e5 s1} x 32 f16.
// ---------------------------------------------------------------------------
__global__ __launch_bounds__(256, 4) void gat_phase2p(
    const f16* __restrict__ h_t,
    const unsigned* __restrict__ srcPK,
    const f16* __restrict__ dstE1,
    const f16* __restrict__ dstE5,
    const unsigned char* __restrict__ emask8,
    float* __restrict__ numA,
    float* __restrict__ denA)
{
    __shared__ f16 Vbuf[2][8320];   // 16640 B per buffer, 33280 B total

    const int t    = threadIdx.x;
    const int lane = t & 63;
    const int wv   = t >> 6;       // 0..3
    const int r    = lane & 15;
    const int q    = lane >> 4;
    const int q8   = q * 8;

    const int hd     = blockIdx.x >> 7;          // 0..7
    const int rowgrp = (blockIdx.x >> 2) & 31;   // 0..31
    const int chunk  = blockIdx.x & 3;           // 0..3
    const int nblk   = rowgrp * 128;
    const int n0     = nblk + wv * 32;
    const int mbase  = chunk * 1024;

    HU s0u, s1u;
    s0u.u = srcPK[hd * N_NODES + n0 + r];
    s1u.u = srcPK[hd * N_NODES + n0 + 16 + r];
    const f16x2 se1_0 = { s0u.h[0], s0u.h[0] };
    const f16x2 se5_0 = { s0u.h[1], s0u.h[1] };
    const f16x2 se1_1 = { s1u.h[0], s1u.h[0] };
    const f16x2 se5_1 = { s1u.h[1], s1u.h[1] };

    // staging sources (advance by it*64 elements/bytes per iteration)
    const f16* Vhead = h_t + (size_t)hd * OUT_FEAT * N_NODES + mbase;
    const f16* srcV  = Vhead + (size_t)(t >> 2) * N_NODES + (t & 3) * 8;
    const unsigned char* srcM =
        emask8 + (size_t)(nblk + (t >> 1)) * N_NODES + mbase + (t & 1) * 16;
    // e staging: 16 threads cover {e1,e5} x {s0,s1} x 32 f16
    const f16* ebase = ((t >> 2) & 1) ? dstE5 : dstE1;
    const f16* esrc  = ebase + (size_t)hd * N_NODES + mbase
                             + (t >> 3) * 32 + (t & 3) * 8;

    f32x4 acc0 = {}, acc1 = {}, acc2 = {}, acc3 = {}, accD0 = {};
    f32x4 acc4 = {}, acc5 = {}, acc6 = {}, acc7 = {}, accD1 = {};
    f16x8 ones;
    #pragma unroll
    for (int j = 0; j < 8; ++j) ones[j] = (f16)1.0f;

    auto stage = [&](int buf, int it) {
        const int c64 = it * 64;
        async_copy16(srcV + c64,      &Vbuf[buf][t * 8]);          // V s0
        async_copy16(srcV + c64 + 32, &Vbuf[buf][2048 + t * 8]);   // V s1
        async_copy16(srcM + c64,      &Vbuf[buf][4096 + t * 8]);   // em s0
        async_copy16(srcM + c64 + 32, &Vbuf[buf][6144 + t * 8]);   // em s1
        if (t < 16) async_copy16(esrc + c64, &Vbuf[buf][8192 + t * 8]);
    };

    stage(0, 0);

    for (int it = 0; it < 16; ++it) {
        const int cur = it & 1;
        __syncthreads();   // drains staged loads for buf[cur]

        stage(1 - cur, (it + 1) & 15);   // wrap: harmless reload on last iter

        #pragma unroll
        for (int s = 0; s < 2; ++s) {
            const int vb = s * 2048;
            uint4 e1v = *(const uint4*)(&Vbuf[cur][8192 + s * 64 + q8]);
            uint4 e5v = *(const uint4*)(&Vbuf[cur][8224 + s * 64 + q8]);
            uint2 m0v = *(const uint2*)(&Vbuf[cur][4096 + s * 2048 + (wv * 32 + r) * 16 + q * 4]);
            uint2 m1v = *(const uint2*)(&Vbuf[cur][4096 + s * 2048 + (wv * 32 + 16 + r) * 16 + q * 4]);

            unsigned e1d[4] = {e1v.x, e1v.y, e1v.z, e1v.w};
            unsigned e5d[4] = {e5v.x, e5v.y, e5v.z, e5v.w};
            unsigned mk0[4], mk1[4];
            mk0[0] = __builtin_amdgcn_perm(0u, m0v.x, 0x01010000u);
            mk0[1] = __builtin_amdgcn_perm(0u, m0v.x, 0x03030202u);
            mk0[2] = __builtin_amdgcn_perm(0u, m0v.y, 0x01010000u);
            mk0[3] = __builtin_amdgcn_perm(0u, m0v.y, 0x03030202u);
            mk1[0] = __builtin_amdgcn_perm(0u, m1v.x, 0x01010000u);
            mk1[1] = __builtin_amdgcn_perm(0u, m1v.x, 0x03030202u);
            mk1[2] = __builtin_amdgcn_perm(0u, m1v.y, 0x01010000u);
            mk1[3] = __builtin_amdgcn_perm(0u, m1v.y, 0x03030202u);

            A8 A0, A1;
            #pragma unroll
            for (int jp = 0; jp < 4; ++jp) {
                HU ed1; ed1.u = e1d[jp];
                HU ed5; ed5.u = e5d[jp];
                HU w0, w1;
                w0.h = __builtin_elementwise_max(se1_0 * ed1.h, se5_0 * ed5.h);
                w1.h = __builtin_elementwise_max(se1_1 * ed1.h, se5_1 * ed5.h);
                A0.u[jp] = w0.u & mk0[jp];
                A1.u[jp] = w1.u & mk1[jp];
            }

            f16x8 b0 = *(const f16x8*)(&Vbuf[cur][vb + (     r) * 32 + q8]);
            f16x8 b1 = *(const f16x8*)(&Vbuf[cur][vb + (16 + r) * 32 + q8]);
            f16x8 b2 = *(const f16x8*)(&Vbuf[cur][vb + (32 + r) * 32 + q8]);
            f16x8 b3 = *(const f16x8*)(&Vbuf[cur][vb + (48 + r) * 32 + q8]);

            acc0  = __builtin_amdgcn_mfma_f32_16x16x32_f16(A0.v, b0,   acc0,  0, 0, 0);
            acc1  = __builtin_amdgcn_mfma_f32_16x16x32_f16(A0.v, b1,   acc1,  0, 0, 0);
            acc2  = __builtin_amdgcn_mfma_f32_16x16x32_f16(A0.v, b2,   acc2,  0, 0, 0);
            acc3  = __builtin_amdgcn_mfma_f32_16x16x32_f16(A0.v, b3,   acc3,  0, 0, 0);
            accD0 = __builtin_amdgcn_mfma_f32_16x16x32_f16(A0.v, ones, accD0, 0, 0, 0);
            acc4  = __builtin_amdgcn_mfma_f32_16x16x32_f16(A1.v, b0,   acc4,  0, 0, 0);
            acc5  = __builtin_amdgcn_mfma_f32_16x16x32_f16(A1.v, b1,   acc5,  0, 0, 0);
            acc6  = __builtin_amdgcn_mfma_f32_16x16x32_f16(A1.v, b2,   acc6,  0, 0, 0);
            acc7  = __builtin_amdgcn_mfma_f32_16x16x32_f16(A1.v, b3,   acc7,  0, 0, 0);
            accD1 = __builtin_amdgcn_mfma_f32_16x16x32_f16(A1.v, ones, accD1, 0, 0, 0);
        }
    }

    #pragma unroll
    for (int reg = 0; reg < 4; ++reg) {
        int row0 = n0 + 4 * q + reg;
        int row1 = row0 + 16;
        atomicAdd(&numA[((size_t)row0 * NHEAD + hd) * 64 +  0 + r], acc0[reg]);
        atomicAdd(&numA[((size_t)row0 * NHEAD + hd) * 64 + 16 + r], acc1[reg]);
        atomicAdd(&numA[((size_t)row0 * NHEAD + hd) * 64 + 32 + r], acc2[reg]);
        atomicAdd(&numA[((size_t)row0 * NHEAD + hd) * 64 + 48 + r], acc3[reg]);
        atomicAdd(&numA[((size_t)row1 * NHEAD + hd) * 64 +  0 + r], acc4[reg]);
        atomicAdd(&numA[((size_t)row1 * NHEAD + hd) * 64 + 16 + r], acc5[reg]);
        atomicAdd(&numA[((size_t)row1 * NHEAD + hd) * 64 + 32 + r], acc6[reg]);
        atomicAdd(&numA[((size_t)row1 * NHEAD + hd) * 64 + 48 + r], acc7[reg]);
        if (r == 0) {
            atomicAdd(&denA[(size_t)row0 * NHEAD + hd], accD0[reg]);
            atomicAdd(&denA[(size_t)row1 * NHEAD + hd], accD1[reg]);
        }
    }
}

// ---------------------------------------------------------------------------
// Combine: divide, mean over heads, ELU. 256 blocks x 512 thr (2 cols/thr).
// ---------------------------------------------------------------------------
__global__ __launch_bounds__(512) void gat_combine(
    const float* __restrict__ numA,
    const float* __restrict__ denA,
    float* __restrict__ out)
{
    int gid = blockIdx.x * 512 + threadIdx.x;   // 0..131071
    int row = gid >> 5;
    int cp  = (gid & 31) * 2;
    float s0 = 0.f, s1 = 0.f;
    #pragma unroll
    for (int h = 0; h < NHEAD; ++h) {
        float2 v = *(const float2*)(numA + ((size_t)row * NHEAD + h) * 64 + cp);
        float inv = 1.f / denA[(size_t)row * NHEAD + h];
        s0 += v.x * inv;
        s1 += v.y * inv;
    }
    s0 *= 0.125f; s1 *= 0.125f;
    float e0 = s0 > 0.f ? s0 : expm1f(s0);
    float e1 = s1 > 0.f ? s1 : expm1f(s1);
    float2 pk = {e0, e1};
    *(float2*)(out + (size_t)row * OUT_FEAT + cp) = pk;
}

// ---------------------------------------------------------------------------
extern "C" void kernel_launch(void* const* d_in, const int* in_sizes, int n_in,
                              void* d_out, int out_size, void* d_ws, size_t ws_size,
                              hipStream_t stream)
{
    const float* x   = (const float*)d_in[0];
    const int*   adj = (const int*)d_in[1];
    const float* W   = (const float*)d_in[2];
    const float* a   = (const float*)d_in[3];
    float* out = (float*)d_out;

    char* ws = (char*)d_ws;
    f16*           h_t   = (f16*)ws;
    unsigned*      srcPK = (unsigned*)(ws + OFF_SRCPK);
    f16*           dstE1 = (f16*)(ws + OFF_DSTE1);
    f16*           dstE5 = (f16*)(ws + OFF_DSTE5);
    f16*           Wt    = (f16*)(ws + OFF_WT);
    unsigned char* em    = (unsigned char*)(ws + OFF_EM);
    float*         numA  = (float*)(ws + OFF_NUMA);
    float*         denA  = (float*)(ws + OFF_DENA);

    gat_pack   <<<2128, 256, 0, stream>>>(adj, (unsigned*)em, W, Wt, numA);
    gat_phase1 <<<512,  256, 0, stream>>>(x, Wt, a, h_t, srcPK, dstE1, dstE5);
    gat_phase2p<<<1024, 256, 0, stream>>>(h_t, srcPK, dstE1, dstE5, em, numA, denA);
    gat_combine<<<256,  512, 0, stream>>>(numA, denA, out);
}

// Round 17
// 165.605 us; speedup vs baseline: 1.2383x; 1.0392x over previous
//
#include <hip/hip_runtime.h>
#include <hip/hip_fp16.h>
#include <cstdint>

#define N_NODES 4096
#define IN_FEAT 256
#define OUT_FEAT 64
#define NHEAD 8
#define LOG2E 1.4426950408889634f

typedef _Float16 f16;
typedef f16   f16x2 __attribute__((ext_vector_type(2)));
typedef f16   f16x8 __attribute__((ext_vector_type(8)));
typedef float f32x4 __attribute__((ext_vector_type(4)));

// ws layout (bytes) — total 30,015,488 (< 38.8 MB proven in r3):
//   h_t   @ 0        : 8*64*4096*2 = 4194304   f16 [h][feat][node]
//   srcPK @ 4194304  : 8*4096*4    = 131072    dword {E1s,E5s} f16 pair per (h,n)
//   dstE1 @ 4325376  : 8*4096*2    = 65536     f16 exp2(t_d) per (h,m)
//   dstE5 @ 4390912  : 8*4096*2    = 65536     f16 exp2(0.2 t_d)
//   (Wt slot unused since r17 — phase1 reads W f32 directly)
//   emask @ 4718592  : 4096*4096   = 16777216  byte 0xFF/0x00 = adj!=0
//   numA  @ 21495808 : 4096*8*64*4 = 8388608   f32 atomic accumulators
//   denA  @ 29884416 : 4096*8*4    = 131072
#define OFF_SRCPK 4194304
#define OFF_DSTE1 4325376
#define OFF_DSTE5 4390912
#define OFF_EM    4718592
#define OFF_NUMA  21495808ULL
#define OFF_DENA  29884416ULL

union HU { unsigned u; f16x2 h; };
union A8 { f16x8 v; unsigned u[4]; };

__device__ __forceinline__ void async_copy16(const void* g, void* l) {
    __builtin_amdgcn_global_load_lds(
        (const __attribute__((address_space(1))) void*)g,
        (__attribute__((address_space(3))) void*)l, 16, 0, 0);
}

static __device__ inline unsigned pkh2(float a, float b) {
    union { f16 h[2]; unsigned u; } t;
    t.h[0] = (f16)a; t.h[1] = (f16)b; return t.u;
}

// ---------------------------------------------------------------------------
// r17 FUSED front end — one dispatch replaces pack+phase1 (4 kernels -> 3).
// The ~112us non-phase2p remainder was invariant under pack/phase1 rewrites
// (r7->r8->r16) => dominated by per-dispatch overhead, not kernel time.
// Branches by blockIdx:
//   [0,512)      phase1: h = x@W[h] (f16 MFMA), W read DIRECTLY as f32
//                (r2 pattern; W is L2-resident; Wt prepack dependency gone)
//   [512,1536)   adj -> emask bytes (elementwise, coalesced)
//   [1536,2576)  zero numA/denA
// MFMA blocks and HBM-streaming emask blocks co-schedule and hide each other.
// ---------------------------------------------------------------------------
__global__ __launch_bounds__(256, 4) void gat_prep(
    const int*   __restrict__ adj,
    unsigned*    __restrict__ em32,
    float*       __restrict__ zeroBase,
    const float* __restrict__ x,      // [4096][256]
    const float* __restrict__ W,      // [8][256][64]
    const float* __restrict__ a,      // [8][128]
    f16*      __restrict__ h_t,
    unsigned* __restrict__ srcPK,
    f16*      __restrict__ dstE1,
    f16*      __restrict__ dstE5)
{
    __shared__ f16 xs[16][264];

    if (blockIdx.x >= 1536) {   // zero branch: 1040 blocks x 2048 floats
        size_t off = ((size_t)(blockIdx.x - 1536) * 256 + threadIdx.x) * 8;
        float4 z = {0.f, 0.f, 0.f, 0.f};
        *(float4*)(zeroBase + off)     = z;
        *(float4*)(zeroBase + off + 4) = z;
        return;
    }
    if (blockIdx.x >= 512) {    // emask branch: wave per row
        const int bi   = blockIdx.x - 512;
        const int wv   = threadIdx.x >> 6;
        const int lane = threadIdx.x & 63;
        const int row  = bi * 4 + wv;
        const int* p   = adj + (size_t)row * N_NODES;
        unsigned* dst  = em32 + (size_t)row * (N_NODES / 4);
        #pragma unroll 4
        for (int s = 0; s < 16; ++s) {
            int4 v = *(const int4*)(p + s * 256 + lane * 4);
            unsigned d = (v.x ? 0x000000FFu : 0u) | (v.y ? 0x0000FF00u : 0u)
                       | (v.z ? 0x00FF0000u : 0u) | (v.w ? 0xFF000000u : 0u);
            dst[s * 64 + lane] = d;
        }
        return;
    }

    // ---- phase1 branch (blocks 0..511) ----
    const int lane = threadIdx.x & 63;
    const int wv   = threadIdx.x >> 6;
    const int tile = blockIdx.x >> 1;
    const int hd   = (blockIdx.x & 1) * 4 + wv;
    const int r    = lane & 15;
    const int q    = lane >> 4;
    const int nb   = tile * 16;

    #pragma unroll
    for (int c = 0; c < 4; ++c) {
        int idx = c * 1024 + threadIdx.x * 4;
        int row = idx >> 8, col = idx & 255;
        float4 v = *(const float4*)(x + (size_t)(nb + row) * IN_FEAT + col);
        uint2 st = { pkh2(v.x, v.y), pkh2(v.z, v.w) };
        *(uint2*)(&xs[row][col]) = st;
    }
    __syncthreads();

    const float* Wg = W + (size_t)hd * (IN_FEAT * OUT_FEAT);
    f32x4 acc[4] = {};

    #pragma unroll 2
    for (int k0 = 0; k0 < IN_FEAT; k0 += 32) {
        f16x8 af = *(const f16x8*)(&xs[r][k0 + q * 8]);
        #pragma unroll
        for (int f = 0; f < 4; ++f) {
            f16x8 bf;   // B[k][col=16f+r], strided f32 loads (L2-resident W)
            #pragma unroll
            for (int j = 0; j < 8; ++j)
                bf[j] = (f16)Wg[(size_t)(k0 + q * 8 + j) * OUT_FEAT + 16 * f + r];
            acc[f] = __builtin_amdgcn_mfma_f32_16x16x32_f16(af, bf, acc[f], 0, 0, 0);
        }
    }

    float asv[4], adv[4];
    #pragma unroll
    for (int f = 0; f < 4; ++f) {
        asv[f] = a[hd * 128 + 16 * f + r];
        adv[f] = a[hd * 128 + 64 + 16 * f + r];
    }
    float sp[4], dp[4];
    #pragma unroll
    for (int reg = 0; reg < 4; ++reg) {
        sp[reg] = acc[0][reg] * asv[0] + acc[1][reg] * asv[1]
                + acc[2][reg] * asv[2] + acc[3][reg] * asv[3];
        dp[reg] = acc[0][reg] * adv[0] + acc[1][reg] * adv[1]
                + acc[2][reg] * adv[2] + acc[3][reg] * adv[3];
    }
    #pragma unroll
    for (int m = 1; m <= 8; m <<= 1) {
        #pragma unroll
        for (int reg = 0; reg < 4; ++reg) {
            sp[reg] += __shfl_xor(sp[reg], m);
            dp[reg] += __shfl_xor(dp[reg], m);
        }
    }

    #pragma unroll
    for (int f = 0; f < 4; ++f) {
        uint2 st = { pkh2(acc[f][0], acc[f][1]), pkh2(acc[f][2], acc[f][3]) };
        *(uint2*)(h_t + (size_t)(hd * OUT_FEAT + 16 * f + r) * N_NODES + nb + 4 * q) = st;
    }

    if (r == 0) {
        #pragma unroll
        for (int reg = 0; reg < 4; ++reg) {
            int row = nb + 4 * q + reg;
            float s = sp[reg] * LOG2E;
            float d = dp[reg] * LOG2E;
            srcPK[hd * N_NODES + row] = pkh2(exp2f(s), exp2f(0.2f * s));
            dstE1[hd * N_NODES + row] = (f16)exp2f(d);
            dstE5[hd * N_NODES + row] = (f16)exp2f(0.2f * d);
        }
    }
}

// ---------------------------------------------------------------------------
// Phase 2 (r16 body, unchanged): grid = 1024 blocks, 256 thr (4 waves).
// Decode: hd = bi>>7, rowgrp = (bi>>2)&31, chunk = bi&3. 64-m tiles,
// 16 iterations, all operands on the double-buffered global_load_lds
// pipeline; zero global loads in the K-loop.
// ---------------------------------------------------------------------------
__global__ __launch_bounds__(256, 4) void gat_phase2p(
    const f16* __restrict__ h_t,
    const unsigned* __restrict__ srcPK,
    const f16* __restrict__ dstE1,
    const f16* __restrict__ dstE5,
    const unsigned char* __restrict__ emask8,
    float* __restrict__ numA,
    float* __restrict__ denA)
{
    __shared__ f16 Vbuf[2][8320];   // 16640 B per buffer

    const int t    = threadIdx.x;
    const int lane = t & 63;
    const int wv   = t >> 6;
    const int r    = lane & 15;
    const int q    = lane >> 4;
    const int q8   = q * 8;

    const int hd     = blockIdx.x >> 7;
    const int rowgrp = (blockIdx.x >> 2) & 31;
    const int chunk  = blockIdx.x & 3;
    const int nblk   = rowgrp * 128;
    const int n0     = nblk + wv * 32;
    const int mbase  = chunk * 1024;

    HU s0u, s1u;
    s0u.u = srcPK[hd * N_NODES + n0 + r];
    s1u.u = srcPK[hd * N_NODES + n0 + 16 + r];
    const f16x2 se1_0 = { s0u.h[0], s0u.h[0] };
    const f16x2 se5_0 = { s0u.h[1], s0u.h[1] };
    const f16x2 se1_1 = { s1u.h[0], s1u.h[0] };
    const f16x2 se5_1 = { s1u.h[1], s1u.h[1] };

    const f16* Vhead = h_t + (size_t)hd * OUT_FEAT * N_NODES + mbase;
    const f16* srcV  = Vhead + (size_t)(t >> 2) * N_NODES + (t & 3) * 8;
    const unsigned char* srcM =
        emask8 + (size_t)(nblk + (t >> 1)) * N_NODES + mbase + (t & 1) * 16;
    const f16* ebase = ((t >> 2) & 1) ? dstE5 : dstE1;
    const f16* esrc  = ebase + (size_t)hd * N_NODES + mbase
                             + (t >> 3) * 32 + (t & 3) * 8;

    f32x4 acc0 = {}, acc1 = {}, acc2 = {}, acc3 = {}, accD0 = {};
    f32x4 acc4 = {}, acc5 = {}, acc6 = {}, acc7 = {}, accD1 = {};
    f16x8 ones;
    #pragma unroll
    for (int j = 0; j < 8; ++j) ones[j] = (f16)1.0f;

    auto stage = [&](int buf, int it) {
        const int c64 = it * 64;
        async_copy16(srcV + c64,      &Vbuf[buf][t * 8]);
        async_copy16(srcV + c64 + 32, &Vbuf[buf][2048 + t * 8]);
        async_copy16(srcM + c64,      &Vbuf[buf][4096 + t * 8]);
        async_copy16(srcM + c64 + 32, &Vbuf[buf][6144 + t * 8]);
        if (t < 16) async_copy16(esrc + c64, &Vbuf[buf][8192 + t * 8]);
    };

    stage(0, 0);

    for (int it = 0; it < 16; ++it) {
        const int cur = it & 1;
        __syncthreads();

        stage(1 - cur, (it + 1) & 15);

        #pragma unroll
        for (int s = 0; s < 2; ++s) {
            const int vb = s * 2048;
            uint4 e1v = *(const uint4*)(&Vbuf[cur][8192 + s * 64 + q8]);
            uint4 e5v = *(const uint4*)(&Vbuf[cur][8224 + s * 64 + q8]);
            uint2 m0v = *(const uint2*)(&Vbuf[cur][4096 + s * 2048 + (wv * 32 + r) * 16 + q * 4]);
            uint2 m1v = *(const uint2*)(&Vbuf[cur][4096 + s * 2048 + (wv * 32 + 16 + r) * 16 + q * 4]);

            unsigned e1d[4] = {e1v.x, e1v.y, e1v.z, e1v.w};
            unsigned e5d[4] = {e5v.x, e5v.y, e5v.z, e5v.w};
            unsigned mk0[4], mk1[4];
            mk0[0] = __builtin_amdgcn_perm(0u, m0v.x, 0x01010000u);
            mk0[1] = __builtin_amdgcn_perm(0u, m0v.x, 0x03030202u);
            mk0[2] = __builtin_amdgcn_perm(0u, m0v.y, 0x01010000u);
            mk0[3] = __builtin_amdgcn_perm(0u, m0v.y, 0x03030202u);
            mk1[0] = __builtin_amdgcn_perm(0u, m1v.x, 0x01010000u);
            mk1[1] = __builtin_amdgcn_perm(0u, m1v.x, 0x03030202u);
            mk1[2] = __builtin_amdgcn_perm(0u, m1v.y, 0x01010000u);
            mk1[3] = __builtin_amdgcn_perm(0u, m1v.y, 0x03030202u);

            A8 A0, A1;
            #pragma unroll
            for (int jp = 0; jp < 4; ++jp) {
                HU ed1; ed1.u = e1d[jp];
                HU ed5; ed5.u = e5d[jp];
                HU w0, w1;
                w0.h = __builtin_elementwise_max(se1_0 * ed1.h, se5_0 * ed5.h);
                w1.h = __builtin_elementwise_max(se1_1 * ed1.h, se5_1 * ed5.h);
                A0.u[jp] = w0.u & mk0[jp];
                A1.u[jp] = w1.u & mk1[jp];
            }

            f16x8 b0 = *(const f16x8*)(&Vbuf[cur][vb + (     r) * 32 + q8]);
            f16x8 b1 = *(const f16x8*)(&Vbuf[cur][vb + (16 + r) * 32 + q8]);
            f16x8 b2 = *(const f16x8*)(&Vbuf[cur][vb + (32 + r) * 32 + q8]);
            f16x8 b3 = *(const f16x8*)(&Vbuf[cur][vb + (48 + r) * 32 + q8]);

            acc0  = __builtin_amdgcn_mfma_f32_16x16x32_f16(A0.v, b0,   acc0,  0, 0, 0);
            acc1  = __builtin_amdgcn_mfma_f32_16x16x32_f16(A0.v, b1,   acc1,  0, 0, 0);
            acc2  = __builtin_amdgcn_mfma_f32_16x16x32_f16(A0.v, b2,   acc2,  0, 0, 0);
            acc3  = __builtin_amdgcn_mfma_f32_16x16x32_f16(A0.v, b3,   acc3,  0, 0, 0);
            accD0 = __builtin_amdgcn_mfma_f32_16x16x32_f16(A0.v, ones, accD0, 0, 0, 0);
            acc4  = __builtin_amdgcn_mfma_f32_16x16x32_f16(A1.v, b0,   acc4,  0, 0, 0);
            acc5  = __builtin_amdgcn_mfma_f32_16x16x32_f16(A1.v, b1,   acc5,  0, 0, 0);
            acc6  = __builtin_amdgcn_mfma_f32_16x16x32_f16(A1.v, b2,   acc6,  0, 0, 0);
            acc7  = __builtin_amdgcn_mfma_f32_16x16x32_f16(A1.v, b3,   acc7,  0, 0, 0);
            accD1 = __builtin_amdgcn_mfma_f32_16x16x32_f16(A1.v, ones, accD1, 0, 0, 0);
        }
    }

    #pragma unroll
    for (int reg = 0; reg < 4; ++reg) {
        int row0 = n0 + 4 * q + reg;
        int row1 = row0 + 16;
        atomicAdd(&numA[((size_t)row0 * NHEAD + hd) * 64 +  0 + r], acc0[reg]);
        atomicAdd(&numA[((size_t)row0 * NHEAD + hd) * 64 + 16 + r], acc1[reg]);
        atomicAdd(&numA[((size_t)row0 * NHEAD + hd) * 64 + 32 + r], acc2[reg]);
        atomicAdd(&numA[((size_t)row0 * NHEAD + hd) * 64 + 48 + r], acc3[reg]);
        atomicAdd(&numA[((size_t)row1 * NHEAD + hd) * 64 +  0 + r], acc4[reg]);
        atomicAdd(&numA[((size_t)row1 * NHEAD + hd) * 64 + 16 + r], acc5[reg]);
        atomicAdd(&numA[((size_t)row1 * NHEAD + hd) * 64 + 32 + r], acc6[reg]);
        atomicAdd(&numA[((size_t)row1 * NHEAD + hd) * 64 + 48 + r], acc7[reg]);
        if (r == 0) {
            atomicAdd(&denA[(size_t)row0 * NHEAD + hd], accD0[reg]);
            atomicAdd(&denA[(size_t)row1 * NHEAD + hd], accD1[reg]);
        }
    }
}

// ---------------------------------------------------------------------------
// Combine: divide, mean over heads, ELU. 256 blocks x 512 thr (2 cols/thr).
// ---------------------------------------------------------------------------
__global__ __launch_bounds__(512) void gat_combine(
    const float* __restrict__ numA,
    const float* __restrict__ denA,
    float* __restrict__ out)
{
    int gid = blockIdx.x * 512 + threadIdx.x;   // 0..131071
    int row = gid >> 5;
    int cp  = (gid & 31) * 2;
    float s0 = 0.f, s1 = 0.f;
    #pragma unroll
    for (int h = 0; h < NHEAD; ++h) {
        float2 v = *(const float2*)(numA + ((size_t)row * NHEAD + h) * 64 + cp);
        float inv = 1.f / denA[(size_t)row * NHEAD + h];
        s0 += v.x * inv;
        s1 += v.y * inv;
    }
    s0 *= 0.125f; s1 *= 0.125f;
    float e0 = s0 > 0.f ? s0 : expm1f(s0);
    float e1 = s1 > 0.f ? s1 : expm1f(s1);
    float2 pk = {e0, e1};
    *(float2*)(out + (size_t)row * OUT_FEAT + cp) = pk;
}

// ---------------------------------------------------------------------------
extern "C" void kernel_launch(void* const* d_in, const int* in_sizes, int n_in,
                              void* d_out, int out_size, void* d_ws, size_t ws_size,
                              hipStream_t stream)
{
    const float* x   = (const float*)d_in[0];
    const int*   adj = (const int*)d_in[1];
    const float* W   = (const float*)d_in[2];
    const float* a   = (const float*)d_in[3];
    float* out = (float*)d_out;

    char* ws = (char*)d_ws;
    f16*           h_t   = (f16*)ws;
    unsigned*      srcPK = (unsigned*)(ws + OFF_SRCPK);
    f16*           dstE1 = (f16*)(ws + OFF_DSTE1);
    f16*           dstE5 = (f16*)(ws + OFF_DSTE5);
    unsigned char* em    = (unsigned char*)(ws + OFF_EM);
    float*         numA  = (float*)(ws + OFF_NUMA);
    float*         denA  = (float*)(ws + OFF_DENA);

    gat_prep   <<<2576, 256, 0, stream>>>(adj, (unsigned*)em, numA,
                                          x, W, a, h_t, srcPK, dstE1, dstE5);
    gat_phase2p<<<1024, 256, 0, stream>>>(h_t, srcPK, dstE1, dstE5, em, numA, denA);
    gat_combine<<<256,  512, 0, stream>>>(numA, denA, out);
}